// Round 4
// baseline (1660.209 us; speedup 1.0000x reference)
//
#include <hip/hip_runtime.h>

#define T_ 32
#define B_ 32
#define H_ 128
#define W_ 128
#define C_ 2
#define NP_ 256
#define CF_ 64
#define CP_ 32
#define OUT_ 128

// padded periph image: rows -1..64 (66), px -2..65 (68) * 2ch = 136 floats/row
#define PROW 136
#define PTB  8976    // 66*136 floats per (t,b)

// d_out layout (floats): out(4096) | logits_seq(131072) | sr(2) | active(1) | route(256) | chan(64)
#define OFF_LOGITS 4096
#define OFF_SR     135168
#define OFF_ACTIVE 135170
#define OFF_ROUTE  135171
#define OFF_CHAN   135427

// ws_cnt layout (u32): [0]=active  [1..256]=route  [257..320]=chan  [321]=totf  [322]=totp
#define CNT_N 323

__device__ __forceinline__ float f4c(const float4& v, int i) {
  switch (i & 3) { case 0: return v.x; case 1: return v.y; case 2: return v.z; default: return v.w; }
}

// ---------------- K1: masked stage + patch scores + event count + padded downsample ----------------
__global__ void __launch_bounds__(256) k_pre(const float* __restrict__ x,
    float* __restrict__ scores, float* __restrict__ P, unsigned* __restrict__ active_count) {
  const int blk = blockIdx.x, tb = blk >> 2, chunk = blk & 3;
  const int r0 = chunk * 16;           // periph rows r0..r0+15
  const int tid = threadIdx.x;
  __shared__ float xt[34*256];         // masked raw rows 2r0-1 .. 2r0+32
  __shared__ unsigned wsum[4];
  const float* img = x + (size_t)tb * 32768;
  unsigned cnt = 0;
  for (int i4 = tid; i4 < 34*64; i4 += 256) {
    const int rr = i4 >> 6, off4 = i4 & 63;
    const int xr = 2*r0 - 1 + rr;
    float4 vv = make_float4(0.f, 0.f, 0.f, 0.f);
    if (xr >= 0 && xr < H_) {
      vv = *reinterpret_cast<const float4*>(img + (size_t)xr*256 + off4*4);
      if (rr >= 1 && rr <= 32) {
        cnt += (fabsf(vv.x) > 0.5f) + (fabsf(vv.y) > 0.5f)
             + (fabsf(vv.z) > 0.5f) + (fabsf(vv.w) > 0.5f);
      }
      vv.x = (fabsf(vv.x) > 0.5f) ? vv.x : 0.f;
      vv.y = (fabsf(vv.y) > 0.5f) ? vv.y : 0.f;
      vv.z = (fabsf(vv.z) > 0.5f) ? vv.z : 0.f;
      vv.w = (fabsf(vv.w) > 0.5f) ? vv.w : 0.f;
    }
    *reinterpret_cast<float4*>(&xt[i4*4]) = vv;
  }
  unsigned c64 = cnt;
#pragma unroll
  for (int off = 32; off > 0; off >>= 1) c64 += __shfl_down(c64, off);
  if ((tid & 63) == 0) wsum[tid >> 6] = c64;
  __syncthreads();
  if (tid == 0) atomicAdd(active_count, wsum[0] + wsum[1] + wsum[2] + wsum[3]);
  // ---- patch scores: 64 patches (4 patch-rows x 16), 4 threads/patch ----
  {
    const int patch = tid >> 2, q = tid & 3;
    const int prl = patch >> 4, pc = patch & 15;
    const int row = 1 + prl*8 + q*2;
    float s = 0.f;
#pragma unroll
    for (int r2 = 0; r2 < 2; ++r2)
#pragma unroll
      for (int j = 0; j < 4; ++j) {
        const float4 vv = *reinterpret_cast<const float4*>(&xt[(row + r2)*256 + pc*16 + j*4]);
        s += fabsf(vv.x) + fabsf(vv.y) + fabsf(vv.z) + fabsf(vv.w);
      }
    s += __shfl_down(s, 1);
    s += __shfl_down(s, 2);
    if (q == 0) scores[tb*NP_ + chunk*64 + patch] = s * (1.f/128.f);
  }
  // ---- padded downsample ----
  float* Pt = P + (size_t)tb * PTB;
  if (tid < 128) {                     // zero col pads (px -2,-1,64,65) for our 16 rows
    const int r = tid >> 3, rem = tid & 7;
    const int px4 = rem >> 1, ci = rem & 1;
    const int px = (px4 < 2) ? (px4 - 2) : (62 + px4);
    Pt[(r0 + r + 1)*PROW + (px + 2)*2 + ci] = 0.f;
  }
  if (chunk == 0 && tid < PROW) Pt[tid] = 0.f;            // pad row -1
  if (chunk == 3 && tid < PROW) Pt[65*PROW + tid] = 0.f;  // pad row 64
#pragma unroll
  for (int k = 0; k < 8; ++k) {
    const int idx = k*256 + tid;       // (row16*64+col)*2+ci
    const int ci = idx & 1, rest = idx >> 1;
    const int col = rest & 63, row16 = rest >> 6;
    const int pr = r0 + row16;
    float wy0=0.125f, wy1=0.375f, wy2=0.375f, wy3=0.125f;
    if (pr == 0)       { wy0=0.f;     wy1=3.f/7.f; wy2=3.f/7.f; wy3=1.f/7.f; }
    else if (pr == 63) { wy0=1.f/7.f; wy1=3.f/7.f; wy2=3.f/7.f; wy3=0.f; }
    float wx0=0.125f, wx1=0.375f, wx2=0.375f, wx3=0.125f;
    if (col == 0)       { wx0=0.f;     wx1=3.f/7.f; wx2=3.f/7.f; wx3=1.f/7.f; }
    else if (col == 63) { wx0=1.f/7.f; wx1=3.f/7.f; wx2=3.f/7.f; wx3=0.f; }
    const int lr = 2*row16;            // xt row of tap j=0
    const int cc0 = 2*col - 1;
    float val = 0.f;
#pragma unroll
    for (int j = 0; j < 4; ++j) {
      const float wyj = (j==0)?wy0:(j==1)?wy1:(j==2)?wy2:wy3;
      float h = 0.f;
#pragma unroll
      for (int i = 0; i < 4; ++i) {
        const float wxi = (i==0)?wx0:(i==1)?wx1:(i==2)?wx2:wx3;
        int cc = cc0 + i; cc = cc < 0 ? 0 : (cc > W_-1 ? W_-1 : cc);
        h += wxi * xt[(lr + j)*256 + cc*2 + ci];
      }
      val += wyj * h;
    }
    Pt[(pr + 1)*PROW + (col + 2)*2 + ci] = val;
  }
}

// ---------------- K2: rank+argmax, fovea conv -> saliency -> channel gate ----------------
__global__ void __launch_bounds__(512) k_gate(const float* __restrict__ x,
    const float* __restrict__ scores, const float* __restrict__ wf,
    int2* __restrict__ y0x0, float* __restrict__ chan_gate,
    unsigned* __restrict__ route_count, unsigned* __restrict__ chan_count) {
  const int tb = blockIdx.x, tid = threadIdx.x;
  __shared__ float sm[NP_];
  __shared__ float tile[34*68];        // [34 rows][34 px * 2ch], zero-padded
  __shared__ float salred[512];
  __shared__ float salv[64];
  __shared__ int2 syx;
  if (tid < 256) sm[tid] = scores[tb*NP_ + tid];
  __syncthreads();
  if (tid < 256) {
    const float v = sm[tid];
    int cg = 0, eqb = 0;
    for (int q = 0; q < NP_; ++q) {
      cg  += (sm[q] > v) ? 1 : 0;
      eqb += ((sm[q] == v) && (q < tid)) ? 1 : 0;
    }
    if (cg < 4) atomicAdd(&route_count[tid], 1u);
    if (cg == 0 && eqb == 0) {
      const int cy = (tid >> 4)*8 + 4, cx = (tid & 15)*8 + 4;
      int y0 = cy - 16; y0 = y0 < 0 ? 0 : (y0 > 96 ? 96 : y0);
      int x0 = cx - 16; x0 = x0 < 0 ? 0 : (x0 > 96 ? 96 : x0);
      y0x0[tb] = make_int2(y0, x0);
      syx = make_int2(y0, x0);
    }
  }
  for (int i = tid; i < 34*68; i += 512) tile[i] = 0.f;
  __syncthreads();
  const int2 yx = syx;
  {                                    // fill interior: 32 rows x 16 segs x 2px
    const int row = tid >> 4, seg = tid & 15;
    const float* src = x + (size_t)tb*32768 + (size_t)(yx.x + row)*256 + (yx.y + seg*2)*2;
    float2 a = *reinterpret_cast<const float2*>(src);
    float2 bq = *reinterpret_cast<const float2*>(src + 2);
    a.x  = (fabsf(a.x)  > 0.5f) ? a.x  : 0.f;
    a.y  = (fabsf(a.y)  > 0.5f) ? a.y  : 0.f;
    bq.x = (fabsf(bq.x) > 0.5f) ? bq.x : 0.f;
    bq.y = (fabsf(bq.y) > 0.5f) ? bq.y : 0.f;
    float* dst = &tile[(row + 1)*68 + (seg*2 + 1)*2];
    *reinterpret_cast<float2*>(dst)     = a;
    *reinterpret_cast<float2*>(dst + 2) = bq;
  }
  __syncthreads();
  const int c = tid & 63, grp = tid >> 6, xg = grp & 3, rh = grp >> 2;
  float wreg[18];
#pragma unroll
  for (int k = 0; k < 18; ++k) wreg[k] = wf[k*CF_ + c];
  const float* tbase = &tile[(rh*16)*68 + xg*16];
  float4 wb[3][5];
#pragma unroll
  for (int m = 0; m < 5; ++m) {
    wb[0][m] = *reinterpret_cast<const float4*>(tbase + m*4);
    wb[1][m] = *reinterpret_cast<const float4*>(tbase + 68 + m*4);
  }
  float sal = 0.f;
#pragma unroll
  for (int yy = 0; yy < 16; ++yy) {
#pragma unroll
    for (int m = 0; m < 5; ++m)
      wb[(yy+2)%3][m] = *reinterpret_cast<const float4*>(tbase + (yy+2)*68 + m*4);
#pragma unroll
    for (int k = 0; k < 8; ++k) {
      float acc = 0.f;
#pragma unroll
      for (int dy = 0; dy < 3; ++dy) {
#pragma unroll
        for (int dx = 0; dx < 3; ++dx) {
          const int r = k + dx;
          const float4 f = wb[(yy+dy)%3][r >> 1];
          acc += f4c(f, (r&1)*2)     * wreg[(dy*3+dx)*2]
               + f4c(f, (r&1)*2 + 1) * wreg[(dy*3+dx)*2 + 1];
        }
      }
      sal += fabsf(acc);
    }
  }
  salred[grp*64 + c] = sal;
  __syncthreads();
  if (tid < 64) {
    float s = 0.f;
#pragma unroll
    for (int g = 0; g < 8; ++g) s += salred[g*64 + tid];
    salv[tid] = s * (1.f/1024.f);
  }
  __syncthreads();
  if (tid < 64) {
    const float sv = salv[tid];
    int cg = 0;
    for (int q = 0; q < 64; ++q) cg += (salv[q] > sv) ? 1 : 0;
    const float gate = (cg < 16) ? 1.f : 0.f;
    chan_gate[tb*CF_ + tid] = gate;
    if (gate > 0.f) atomicAdd(&chan_count[tid], 1u);
  }
}

// ---------------- K3: fused persistent membranes, atomic-free, 4px/thread ----------------
// fovea: blocks 0..1023  (b*32+row), 512 thr: c=tid&63, xg=tid>>6 (4px each)
// periph: blocks 1024..3071 (b*64+row), 512 thr: c=tid&31, xg=tid>>5 (4px each)
__global__ void __launch_bounds__(512, 8) k_mem(const float* __restrict__ x,
    const float* __restrict__ P, const float* __restrict__ wf, const float* __restrict__ wp,
    const int2* __restrict__ y0x0, const float* __restrict__ chan_gate,
    unsigned char* __restrict__ fov_part, unsigned char* __restrict__ per_part) {
  const int tid = threadIdx.x;
  if (blockIdx.x < 1024) {
    const int blk = blockIdx.x, b = blk >> 5, row = blk & 31;
    const int c = tid & 63, xg = tid >> 6, px0 = xg * 4;
    float wreg[18];
#pragma unroll
    for (int k = 0; k < 18; ++k) wreg[k] = wf[k*CF_ + c];
    float v[4] = {0.f, 0.f, 0.f, 0.f};
    unsigned pcnt = 0;
    for (int t = 0; t < T_; ++t) {
      const int tb = t*B_ + b;
      const int2 yx = y0x0[tb];
      const float gate = chan_gate[tb*CF_ + c];
      float acc[4] = {0.f, 0.f, 0.f, 0.f};
      const float* img = x + (size_t)tb*32768 + yx.y*2;
#pragma unroll
      for (int rr = 0; rr < 3; ++rr) {
        const int wr = row - 1 + rr;
        float2 rb[6];
        if (wr >= 0 && wr < 32) {      // block-uniform
          const float* rp = img + (size_t)(yx.x + wr)*256;
          if (xg == 0) {               // wave-uniform
            rb[0] = make_float2(0.f, 0.f);
#pragma unroll
            for (int j = 1; j < 6; ++j)
              rb[j] = *reinterpret_cast<const float2*>(rp + (j - 1)*2);
          } else if (xg == 7) {
#pragma unroll
            for (int j = 0; j < 5; ++j)
              rb[j] = *reinterpret_cast<const float2*>(rp + (px0 - 1 + j)*2);
            rb[5] = make_float2(0.f, 0.f);
          } else {
#pragma unroll
            for (int j = 0; j < 6; ++j)
              rb[j] = *reinterpret_cast<const float2*>(rp + (px0 - 1 + j)*2);
          }
#pragma unroll
          for (int j = 0; j < 6; ++j) {
            rb[j].x = (fabsf(rb[j].x) > 0.5f) ? rb[j].x : 0.f;
            rb[j].y = (fabsf(rb[j].y) > 0.5f) ? rb[j].y : 0.f;
          }
        } else {
#pragma unroll
          for (int j = 0; j < 6; ++j) rb[j] = make_float2(0.f, 0.f);
        }
#pragma unroll
        for (int k = 0; k < 4; ++k)
#pragma unroll
          for (int dx = 0; dx < 3; ++dx) {
            const float2 f = rb[k + dx];
            acc[k] += f.x*wreg[(rr*3+dx)*2] + f.y*wreg[(rr*3+dx)*2 + 1];
          }
      }
      unsigned cnt = 0;
#pragma unroll
      for (int k = 0; k < 4; ++k) {
        float nv = 0.9f*v[k] + acc[k]*gate;
        if (nv > 1.0f) { nv -= 1.0f; ++cnt; }
        v[k] = nv;
      }
      if (t & 1) {
        const size_t fa = ((((size_t)(t >> 1)*B_ + b)*32 + row)*8 + xg)*64 + c;
        fov_part[fa] = (unsigned char)(pcnt | (cnt << 4));
      } else pcnt = cnt;
    }
  } else {
    const int pb = blockIdx.x - 1024, b = pb >> 6, row = pb & 63;
    const int c = tid & 31, xg = tid >> 5, px0 = xg * 4;
    float wreg[18];
#pragma unroll
    for (int k = 0; k < 18; ++k) wreg[k] = wp[k*CP_ + c];
    float v[4] = {0.f, 0.f, 0.f, 0.f};
    unsigned pcnt = 0;
    for (int t = 0; t < T_; ++t) {
      const int tb = t*B_ + b;
      const float* Pt = P + (size_t)tb*PTB + (size_t)row*PROW + (px0 + 1)*2;
      float acc[4] = {0.f, 0.f, 0.f, 0.f};
#pragma unroll
      for (int rr = 0; rr < 3; ++rr) {
        float2 rb[6];
#pragma unroll
        for (int j = 0; j < 6; ++j)
          rb[j] = *reinterpret_cast<const float2*>(Pt + rr*PROW + j*2);
#pragma unroll
        for (int k = 0; k < 4; ++k)
#pragma unroll
          for (int dx = 0; dx < 3; ++dx) {
            const float2 f = rb[k + dx];
            acc[k] += f.x*wreg[(rr*3+dx)*2] + f.y*wreg[(rr*3+dx)*2 + 1];
          }
      }
      unsigned cnt = 0;
#pragma unroll
      for (int k = 0; k < 4; ++k) {
        float nv = 0.9f*v[k] + acc[k];
        if (nv > 1.0f) { nv -= 1.0f; ++cnt; }
        v[k] = nv;
      }
      cnt += __shfl_down(cnt, 32);     // combine the wave's two xg halves
      if (t & 1) {
        if ((tid & 63) < 32) {
          const size_t pa = ((((size_t)(t >> 1)*B_ + b)*64 + row)*8 + (xg >> 1))*32 + c;
          per_part[pa] = (unsigned char)(pcnt | (cnt << 4));
        }
      } else pcnt = cnt;
    }
  }
}

// ---------------- K4: reduce partials + logits ----------------
__global__ void __launch_bounds__(256) k_logits(const float* __restrict__ scores,
    const unsigned char* __restrict__ fov_part, const unsigned char* __restrict__ per_part,
    const float* __restrict__ head_w, const float* __restrict__ head_b,
    const float* __restrict__ route_w, const float* __restrict__ route_b,
    float* __restrict__ logits, unsigned* __restrict__ tot) {
  const int tb = blockIdx.x, tid = threadIdx.x;
  const int t = tb >> 5, b = tb & 31;
  __shared__ float sc[NP_];
  __shared__ float fu[96];
  __shared__ unsigned pred[4][32];
  sc[tid] = scores[tb*NP_ + tid];      // tid<256 covers all
  const bool hi = (t & 1);
  if (tid < 64) {
    const unsigned char* fp = fov_part + ((size_t)(t >> 1)*B_ + b)*16384;
    unsigned fsum = 0;
#pragma unroll 8
    for (int i = 0; i < 256; ++i) {
      const unsigned byte = fp[i*64 + tid];
      fsum += hi ? (byte >> 4) : (byte & 15u);
    }
    fu[tid] = (float)fsum * (1.f/1024.f);
    unsigned r = fsum;
#pragma unroll
    for (int off = 32; off > 0; off >>= 1) r += __shfl_down(r, off);
    if (tid == 0) atomicAdd(&tot[0], r);
  } else if (tid < 192) {
    const int idx = tid - 64, c = idx & 31, q = idx >> 5;  // q 0..3
    const unsigned char* pp = per_part + ((size_t)(t >> 1)*B_ + b)*16384;
    unsigned psum = 0;
#pragma unroll 8
    for (int i = q*128; i < q*128 + 128; ++i) {
      const unsigned byte = pp[i*32 + c];
      psum += hi ? (byte >> 4) : (byte & 15u);
    }
    pred[q][c] = psum;
    unsigned r = psum;
#pragma unroll
    for (int off = 32; off > 0; off >>= 1) r += __shfl_down(r, off);
    if ((tid & 63) == 0) atomicAdd(&tot[1], r);
  }
  __syncthreads();
  if (tid >= 64 && tid < 96) {
    const int c = tid - 64;
    fu[64 + c] = (float)(pred[0][c] + pred[1][c] + pred[2][c] + pred[3][c]) * (1.f/4096.f);
  }
  __syncthreads();
  if (tid < 128) {
    const int o = tid;
    float acc = head_b[o] + route_b[o];
#pragma unroll 8
    for (int k = 0; k < 96; ++k)  acc += fu[k]*head_w[k*OUT_ + o];
#pragma unroll 8
    for (int p = 0; p < NP_; ++p) acc += sc[p]*route_w[p*OUT_ + o];
    logits[tb*OUT_ + o] = acc;
  }
}

// ---------------- K5: finalize ----------------
__global__ void __launch_bounds__(256) k_final(const float* __restrict__ logits,
    float* __restrict__ dout, const unsigned* __restrict__ cnts) {
  const int blk = blockIdx.x, tid = threadIdx.x;
  if (blk < 16) {
    const int idx = blk*256 + tid;
    const int b = idx >> 7, o = idx & 127;
    float s = 0.f;
#pragma unroll
    for (int t = 0; t < T_; ++t) s += logits[(t*B_ + b)*OUT_ + o];
    dout[idx] = s * (1.f/32.f);
  } else {
    if (tid == 0) {
      dout[OFF_SR]     = (float)cnts[321] * (1.f/67108864.f);   // T*B*32*32*64
      dout[OFF_SR + 1] = (float)cnts[322] * (1.f/134217728.f);  // T*B*64*64*32
      dout[OFF_ACTIVE] = (float)cnts[0]   * (1.f/33554432.f);   // T*B*H*W*C
    }
    dout[OFF_ROUTE + tid] = (float)cnts[1 + tid] * (1.f/1024.f);
    if (tid < 64) dout[OFF_CHAN + tid] = (float)cnts[257 + tid] * (1.f/1024.f);
  }
}

extern "C" void kernel_launch(void* const* d_in, const int* in_sizes, int n_in,
                              void* d_out, int out_size, void* d_ws, size_t ws_size,
                              hipStream_t stream) {
  const float* x       = (const float*)d_in[0];
  const float* wf      = (const float*)d_in[1];
  const float* wp      = (const float*)d_in[2];
  const float* head_w  = (const float*)d_in[3];
  const float* head_b  = (const float*)d_in[4];
  const float* route_w = (const float*)d_in[5];
  const float* route_b = (const float*)d_in[6];
  float* out = (float*)d_out;

  float*         ws_P      = (float*)d_ws;                    // 1024*8976 floats
  float*         ws_scores = ws_P + (size_t)1024*PTB;         // 262144 floats
  float*         ws_gate   = ws_scores + T_*B_*NP_;           // 65536 floats
  int2*          ws_yx     = (int2*)(ws_gate + T_*B_*CF_);    // 1024 int2
  unsigned char* fov_part  = (unsigned char*)(ws_yx + T_*B_); // 16*32*32*8*64 = 8 MB
  unsigned char* per_part  = fov_part + (size_t)16*32*32*8*64;// 16*32*64*8*32 = 8 MB
  unsigned*      ws_cnt    = (unsigned*)(per_part + (size_t)16*32*64*8*32);

  hipMemsetAsync(ws_cnt, 0, CNT_N*sizeof(unsigned), stream);

  k_pre   <<<T_*B_*4, 256, 0, stream>>>(x, ws_scores, ws_P, ws_cnt);
  k_gate  <<<T_*B_,   512, 0, stream>>>(x, ws_scores, wf, ws_yx, ws_gate,
                                        ws_cnt + 1, ws_cnt + 257);
  k_mem   <<<3072,    512, 0, stream>>>(x, ws_P, wf, wp, ws_yx, ws_gate,
                                        fov_part, per_part);
  k_logits<<<T_*B_,   256, 0, stream>>>(ws_scores, fov_part, per_part, head_w, head_b,
                                        route_w, route_b, out + OFF_LOGITS, ws_cnt + 321);
  k_final <<<17, 256, 0, stream>>>(out + OFF_LOGITS, out, ws_cnt);
}

// Round 5
// 546.176 us; speedup vs baseline: 3.0397x; 3.0397x over previous
//
#include <hip/hip_runtime.h>

#define T_ 32
#define B_ 32
#define H_ 128
#define W_ 128
#define C_ 2
#define NP_ 256
#define CF_ 64
#define CP_ 32
#define OUT_ 128

// padded periph image: rows -1..64 (66), px -2..65 (68) * 2ch = 136 floats/row
#define PROW 136
#define PTB  8976    // 66*136 floats per (t,b)

// d_out layout (floats): out(4096) | logits_seq(131072) | sr(2) | active(1) | route(256) | chan(64)
#define OFF_LOGITS 4096
#define OFF_SR     135168
#define OFF_ACTIVE 135170
#define OFF_ROUTE  135171
#define OFF_CHAN   135427

// ws_cnt layout (u32): [0]=active  [1..256]=route  [257..320]=chan  [321]=totf  [322]=totp
#define CNT_N 323

__device__ __forceinline__ float f4c(const float4& v, int i) {
  switch (i & 3) { case 0: return v.x; case 1: return v.y; case 2: return v.z; default: return v.w; }
}

// ---------------- K1: masked stage + patch scores + event count + padded downsample ----------------
__global__ void __launch_bounds__(256) k_pre(const float* __restrict__ x,
    float* __restrict__ scores, float* __restrict__ P, unsigned* __restrict__ active_count) {
  const int blk = blockIdx.x, tb = blk >> 2, chunk = blk & 3;
  const int r0 = chunk * 16;           // periph rows r0..r0+15
  const int tid = threadIdx.x;
  __shared__ float xt[34*256];         // masked raw rows 2r0-1 .. 2r0+32
  __shared__ unsigned wsum[4];
  const float* img = x + (size_t)tb * 32768;
  unsigned cnt = 0;
  for (int i4 = tid; i4 < 34*64; i4 += 256) {
    const int rr = i4 >> 6, off4 = i4 & 63;
    const int xr = 2*r0 - 1 + rr;
    float4 vv = make_float4(0.f, 0.f, 0.f, 0.f);
    if (xr >= 0 && xr < H_) {
      vv = *reinterpret_cast<const float4*>(img + (size_t)xr*256 + off4*4);
      if (rr >= 1 && rr <= 32) {
        cnt += (fabsf(vv.x) > 0.5f) + (fabsf(vv.y) > 0.5f)
             + (fabsf(vv.z) > 0.5f) + (fabsf(vv.w) > 0.5f);
      }
      vv.x = (fabsf(vv.x) > 0.5f) ? vv.x : 0.f;
      vv.y = (fabsf(vv.y) > 0.5f) ? vv.y : 0.f;
      vv.z = (fabsf(vv.z) > 0.5f) ? vv.z : 0.f;
      vv.w = (fabsf(vv.w) > 0.5f) ? vv.w : 0.f;
    }
    *reinterpret_cast<float4*>(&xt[i4*4]) = vv;
  }
  unsigned c64 = cnt;
#pragma unroll
  for (int off = 32; off > 0; off >>= 1) c64 += __shfl_down(c64, off);
  if ((tid & 63) == 0) wsum[tid >> 6] = c64;
  __syncthreads();
  if (tid == 0) atomicAdd(active_count, wsum[0] + wsum[1] + wsum[2] + wsum[3]);
  // ---- patch scores: 64 patches (4 patch-rows x 16), 4 threads/patch ----
  {
    const int patch = tid >> 2, q = tid & 3;
    const int prl = patch >> 4, pc = patch & 15;
    const int row = 1 + prl*8 + q*2;
    float s = 0.f;
#pragma unroll
    for (int r2 = 0; r2 < 2; ++r2)
#pragma unroll
      for (int j = 0; j < 4; ++j) {
        const float4 vv = *reinterpret_cast<const float4*>(&xt[(row + r2)*256 + pc*16 + j*4]);
        s += fabsf(vv.x) + fabsf(vv.y) + fabsf(vv.z) + fabsf(vv.w);
      }
    s += __shfl_down(s, 1);
    s += __shfl_down(s, 2);
    if (q == 0) scores[tb*NP_ + chunk*64 + patch] = s * (1.f/128.f);
  }
  // ---- padded downsample ----
  float* Pt = P + (size_t)tb * PTB;
  if (tid < 128) {                     // zero col pads (px -2,-1,64,65) for our 16 rows
    const int r = tid >> 3, rem = tid & 7;
    const int px4 = rem >> 1, ci = rem & 1;
    const int px = (px4 < 2) ? (px4 - 2) : (62 + px4);
    Pt[(r0 + r + 1)*PROW + (px + 2)*2 + ci] = 0.f;
  }
  if (chunk == 0 && tid < PROW) Pt[tid] = 0.f;            // pad row -1
  if (chunk == 3 && tid < PROW) Pt[65*PROW + tid] = 0.f;  // pad row 64
#pragma unroll
  for (int k = 0; k < 8; ++k) {
    const int idx = k*256 + tid;       // (row16*64+col)*2+ci
    const int ci = idx & 1, rest = idx >> 1;
    const int col = rest & 63, row16 = rest >> 6;
    const int pr = r0 + row16;
    float wy0=0.125f, wy1=0.375f, wy2=0.375f, wy3=0.125f;
    if (pr == 0)       { wy0=0.f;     wy1=3.f/7.f; wy2=3.f/7.f; wy3=1.f/7.f; }
    else if (pr == 63) { wy0=1.f/7.f; wy1=3.f/7.f; wy2=3.f/7.f; wy3=0.f; }
    float wx0=0.125f, wx1=0.375f, wx2=0.375f, wx3=0.125f;
    if (col == 0)       { wx0=0.f;     wx1=3.f/7.f; wx2=3.f/7.f; wx3=1.f/7.f; }
    else if (col == 63) { wx0=1.f/7.f; wx1=3.f/7.f; wx2=3.f/7.f; wx3=0.f; }
    const int lr = 2*row16;            // xt row of tap j=0
    const int cc0 = 2*col - 1;
    float val = 0.f;
#pragma unroll
    for (int j = 0; j < 4; ++j) {
      const float wyj = (j==0)?wy0:(j==1)?wy1:(j==2)?wy2:wy3;
      float h = 0.f;
#pragma unroll
      for (int i = 0; i < 4; ++i) {
        const float wxi = (i==0)?wx0:(i==1)?wx1:(i==2)?wx2:wx3;
        int cc = cc0 + i; cc = cc < 0 ? 0 : (cc > W_-1 ? W_-1 : cc);
        h += wxi * xt[(lr + j)*256 + cc*2 + ci];
      }
      val += wyj * h;
    }
    Pt[(pr + 1)*PROW + (col + 2)*2 + ci] = val;
  }
}

// ---------------- K2: rank+argmax, fovea conv -> saliency -> channel gate ----------------
__global__ void __launch_bounds__(512) k_gate(const float* __restrict__ x,
    const float* __restrict__ scores, const float* __restrict__ wf,
    int2* __restrict__ y0x0, float* __restrict__ chan_gate,
    unsigned* __restrict__ route_count, unsigned* __restrict__ chan_count) {
  const int tb = blockIdx.x, tid = threadIdx.x;
  __shared__ float sm[NP_];
  __shared__ float tile[34*68];        // [34 rows][34 px * 2ch], zero-padded
  __shared__ float salred[512];
  __shared__ float salv[64];
  __shared__ int2 syx;
  if (tid < 256) sm[tid] = scores[tb*NP_ + tid];
  __syncthreads();
  if (tid < 256) {
    const float v = sm[tid];
    int cg = 0, eqb = 0;
    for (int q = 0; q < NP_; ++q) {
      cg  += (sm[q] > v) ? 1 : 0;
      eqb += ((sm[q] == v) && (q < tid)) ? 1 : 0;
    }
    if (cg < 4) atomicAdd(&route_count[tid], 1u);
    if (cg == 0 && eqb == 0) {
      const int cy = (tid >> 4)*8 + 4, cx = (tid & 15)*8 + 4;
      int y0 = cy - 16; y0 = y0 < 0 ? 0 : (y0 > 96 ? 96 : y0);
      int x0 = cx - 16; x0 = x0 < 0 ? 0 : (x0 > 96 ? 96 : x0);
      y0x0[tb] = make_int2(y0, x0);
      syx = make_int2(y0, x0);
    }
  }
  for (int i = tid; i < 34*68; i += 512) tile[i] = 0.f;
  __syncthreads();
  const int2 yx = syx;
  {                                    // fill interior: 32 rows x 16 segs x 2px
    const int row = tid >> 4, seg = tid & 15;
    const float* src = x + (size_t)tb*32768 + (size_t)(yx.x + row)*256 + (yx.y + seg*2)*2;
    float2 a = *reinterpret_cast<const float2*>(src);
    float2 bq = *reinterpret_cast<const float2*>(src + 2);
    a.x  = (fabsf(a.x)  > 0.5f) ? a.x  : 0.f;
    a.y  = (fabsf(a.y)  > 0.5f) ? a.y  : 0.f;
    bq.x = (fabsf(bq.x) > 0.5f) ? bq.x : 0.f;
    bq.y = (fabsf(bq.y) > 0.5f) ? bq.y : 0.f;
    float* dst = &tile[(row + 1)*68 + (seg*2 + 1)*2];
    *reinterpret_cast<float2*>(dst)     = a;
    *reinterpret_cast<float2*>(dst + 2) = bq;
  }
  __syncthreads();
  const int c = tid & 63, grp = tid >> 6, xg = grp & 3, rh = grp >> 2;
  float wreg[18];
#pragma unroll
  for (int k = 0; k < 18; ++k) wreg[k] = wf[k*CF_ + c];
  const float* tbase = &tile[(rh*16)*68 + xg*16];
  float4 wb[3][5];
#pragma unroll
  for (int m = 0; m < 5; ++m) {
    wb[0][m] = *reinterpret_cast<const float4*>(tbase + m*4);
    wb[1][m] = *reinterpret_cast<const float4*>(tbase + 68 + m*4);
  }
  float sal = 0.f;
#pragma unroll
  for (int yy = 0; yy < 16; ++yy) {
#pragma unroll
    for (int m = 0; m < 5; ++m)
      wb[(yy+2)%3][m] = *reinterpret_cast<const float4*>(tbase + (yy+2)*68 + m*4);
#pragma unroll
    for (int k = 0; k < 8; ++k) {
      float acc = 0.f;
#pragma unroll
      for (int dy = 0; dy < 3; ++dy) {
#pragma unroll
        for (int dx = 0; dx < 3; ++dx) {
          const int r = k + dx;
          const float4 f = wb[(yy+dy)%3][r >> 1];
          acc += f4c(f, (r&1)*2)     * wreg[(dy*3+dx)*2]
               + f4c(f, (r&1)*2 + 1) * wreg[(dy*3+dx)*2 + 1];
        }
      }
      sal += fabsf(acc);
    }
  }
  salred[grp*64 + c] = sal;
  __syncthreads();
  if (tid < 64) {
    float s = 0.f;
#pragma unroll
    for (int g = 0; g < 8; ++g) s += salred[g*64 + tid];
    salv[tid] = s * (1.f/1024.f);
  }
  __syncthreads();
  if (tid < 64) {
    const float sv = salv[tid];
    int cg = 0;
    for (int q = 0; q < 64; ++q) cg += (salv[q] > sv) ? 1 : 0;
    const float gate = (cg < 16) ? 1.f : 0.f;
    chan_gate[tb*CF_ + tid] = gate;
    if (gate > 0.f) atomicAdd(&chan_count[tid], 1u);
  }
}

// ---------------- K3: fused persistent membranes, atomic-free, 4px/thread, no spills ----------------
// fovea:  blocks 0..2047    = b*64 + row*2 + chalf;  256 thr: c_lo=tid&31, xg=tid>>5 (4px)
// periph: blocks 2048..6143 = 2048 + b*128 + row*2 + colhalf; same thread layout
// partial layout fovea:  [t2][b][row][chalf][wave][c_lo]  (4.2 MB)
// partial layout periph: [t2][b][row][half][wave][c]      (8.4 MB)
__global__ void __launch_bounds__(256, 4) k_mem(const float* __restrict__ x,
    const float* __restrict__ P, const float* __restrict__ wf, const float* __restrict__ wp,
    const int2* __restrict__ y0x0, const float* __restrict__ chan_gate,
    unsigned char* __restrict__ fov_part, unsigned char* __restrict__ per_part) {
  const int tid = threadIdx.x;
  const int c_lo = tid & 31, xg = tid >> 5, w = tid >> 6;
  if (blockIdx.x < 2048) {
    const int blk = blockIdx.x, b = blk >> 6, sub = blk & 63;
    const int row = sub >> 1, chalf = sub & 1;
    const int c = chalf*32 + c_lo, px0 = xg*4;
    float wreg[18];
#pragma unroll
    for (int k = 0; k < 18; ++k) wreg[k] = wf[k*CF_ + c];
    float v[4] = {0.f, 0.f, 0.f, 0.f};
    unsigned pcnt = 0;
    for (int t = 0; t < T_; ++t) {
      const int tb = t*B_ + b;
      const int2 yx = y0x0[tb];
      const float gate = chan_gate[tb*CF_ + c];
      float acc[4] = {0.f, 0.f, 0.f, 0.f};
      const float* img = x + (size_t)tb*32768 + yx.y*2;
#pragma unroll
      for (int rr = 0; rr < 3; ++rr) {
        const int wr = row - 1 + rr;
        float2 rb[6];
        if (wr >= 0 && wr < 32) {      // block-uniform
          const float* rp = img + (size_t)(yx.x + wr)*256;
          if (xg == 0) {               // half-wave-uniform
            rb[0] = make_float2(0.f, 0.f);
#pragma unroll
            for (int j = 1; j < 6; ++j)
              rb[j] = *reinterpret_cast<const float2*>(rp + (j - 1)*2);
          } else if (xg == 7) {
#pragma unroll
            for (int j = 0; j < 5; ++j)
              rb[j] = *reinterpret_cast<const float2*>(rp + (27 + j)*2);
            rb[5] = make_float2(0.f, 0.f);
          } else {
#pragma unroll
            for (int j = 0; j < 6; ++j)
              rb[j] = *reinterpret_cast<const float2*>(rp + (px0 - 1 + j)*2);
          }
#pragma unroll
          for (int j = 0; j < 6; ++j) {
            rb[j].x = (fabsf(rb[j].x) > 0.5f) ? rb[j].x : 0.f;
            rb[j].y = (fabsf(rb[j].y) > 0.5f) ? rb[j].y : 0.f;
          }
        } else {
#pragma unroll
          for (int j = 0; j < 6; ++j) rb[j] = make_float2(0.f, 0.f);
        }
#pragma unroll
        for (int k = 0; k < 4; ++k)
#pragma unroll
          for (int dx = 0; dx < 3; ++dx) {
            const float2 f = rb[k + dx];
            acc[k] += f.x*wreg[(rr*3+dx)*2] + f.y*wreg[(rr*3+dx)*2 + 1];
          }
      }
      unsigned cnt = 0;
#pragma unroll
      for (int k = 0; k < 4; ++k) {
        float nv = 0.9f*v[k] + acc[k]*gate;
        if (nv > 1.0f) { nv -= 1.0f; ++cnt; }
        v[k] = nv;
      }
      const unsigned m = cnt + __shfl_down(cnt, 32);   // merge xg pair -> 8px
      if (t & 1) {
        if ((tid & 63) < 32) {
          const size_t fa = (((((size_t)(t >> 1)*B_ + b)*32 + row)*2 + chalf)*4 + w)*32 + c_lo;
          fov_part[fa] = (unsigned char)(pcnt | (m << 4));
        }
      } else pcnt = m;
    }
  } else {
    const int pb = blockIdx.x - 2048, b = pb >> 7, sub = pb & 127;
    const int row = sub >> 1, half = sub & 1;
    const int px0 = half*32 + xg*4;
    float wreg[18];
#pragma unroll
    for (int k = 0; k < 18; ++k) wreg[k] = wp[k*CP_ + c_lo];
    float v[4] = {0.f, 0.f, 0.f, 0.f};
    unsigned pcnt = 0;
    for (int t = 0; t < T_; ++t) {
      const int tb = t*B_ + b;
      const float* Pt = P + (size_t)tb*PTB + (size_t)row*PROW + (px0 + 1)*2;
      float acc[4] = {0.f, 0.f, 0.f, 0.f};
#pragma unroll
      for (int rr = 0; rr < 3; ++rr) {
        float2 rb[6];
#pragma unroll
        for (int j = 0; j < 6; ++j)
          rb[j] = *reinterpret_cast<const float2*>(Pt + rr*PROW + j*2);
#pragma unroll
        for (int k = 0; k < 4; ++k)
#pragma unroll
          for (int dx = 0; dx < 3; ++dx) {
            const float2 f = rb[k + dx];
            acc[k] += f.x*wreg[(rr*3+dx)*2] + f.y*wreg[(rr*3+dx)*2 + 1];
          }
      }
      unsigned cnt = 0;
#pragma unroll
      for (int k = 0; k < 4; ++k) {
        float nv = 0.9f*v[k] + acc[k];
        if (nv > 1.0f) { nv -= 1.0f; ++cnt; }
        v[k] = nv;
      }
      const unsigned m = cnt + __shfl_down(cnt, 32);   // merge xg pair -> 8px
      if (t & 1) {
        if ((tid & 63) < 32) {
          const size_t pa = (((((size_t)(t >> 1)*B_ + b)*64 + row)*2 + half)*4 + w)*32 + c_lo;
          per_part[pa] = (unsigned char)(pcnt | (m << 4));
        }
      } else pcnt = m;
    }
  }
}

// ---------------- K4: reduce partials + logits ----------------
__global__ void __launch_bounds__(256) k_logits(const float* __restrict__ scores,
    const unsigned char* __restrict__ fov_part, const unsigned char* __restrict__ per_part,
    const float* __restrict__ head_w, const float* __restrict__ head_b,
    const float* __restrict__ route_w, const float* __restrict__ route_b,
    float* __restrict__ logits, unsigned* __restrict__ tot) {
  const int tb = blockIdx.x, tid = threadIdx.x;
  const int t = tb >> 5, b = tb & 31;
  __shared__ float sc[NP_];
  __shared__ float fu[96];
  __shared__ unsigned pred[4][32];
  sc[tid] = scores[tb*NP_ + tid];
  const bool hi = (t & 1);
  if (tid < 64) {
    const unsigned char* fp = fov_part + ((size_t)(t >> 1)*B_ + b)*8192;
    const int chalf = tid >> 5, cl = tid & 31;
    unsigned fsum = 0;
    for (int row = 0; row < 32; ++row)
#pragma unroll
      for (int wv = 0; wv < 4; ++wv) {
        const unsigned byte = fp[row*256 + chalf*128 + wv*32 + cl];
        fsum += hi ? (byte >> 4) : (byte & 15u);
      }
    fu[tid] = (float)fsum * (1.f/1024.f);
    unsigned r = fsum;
#pragma unroll
    for (int off = 32; off > 0; off >>= 1) r += __shfl_down(r, off);
    if (tid == 0) atomicAdd(&tot[0], r);
  } else if (tid < 192) {
    const int idx = tid - 64, c = idx & 31, q = idx >> 5;  // q 0..3
    const unsigned char* pp = per_part + ((size_t)(t >> 1)*B_ + b)*16384;
    unsigned psum = 0;
    for (int row = q*16; row < q*16 + 16; ++row)
#pragma unroll
      for (int hw = 0; hw < 8; ++hw) {   // half*4+wave
        const unsigned byte = pp[row*256 + hw*32 + c];
        psum += hi ? (byte >> 4) : (byte & 15u);
      }
    pred[q][c] = psum;
    unsigned r = psum;
#pragma unroll
    for (int off = 32; off > 0; off >>= 1) r += __shfl_down(r, off);
    if ((tid & 63) == 0) atomicAdd(&tot[1], r);
  }
  __syncthreads();
  if (tid >= 64 && tid < 96) {
    const int c = tid - 64;
    fu[64 + c] = (float)(pred[0][c] + pred[1][c] + pred[2][c] + pred[3][c]) * (1.f/4096.f);
  }
  __syncthreads();
  if (tid < 128) {
    const int o = tid;
    float acc = head_b[o] + route_b[o];
#pragma unroll 8
    for (int k = 0; k < 96; ++k)  acc += fu[k]*head_w[k*OUT_ + o];
#pragma unroll 8
    for (int p = 0; p < NP_; ++p) acc += sc[p]*route_w[p*OUT_ + o];
    logits[tb*OUT_ + o] = acc;
  }
}

// ---------------- K5: finalize ----------------
__global__ void __launch_bounds__(256) k_final(const float* __restrict__ logits,
    float* __restrict__ dout, const unsigned* __restrict__ cnts) {
  const int blk = blockIdx.x, tid = threadIdx.x;
  if (blk < 16) {
    const int idx = blk*256 + tid;
    const int b = idx >> 7, o = idx & 127;
    float s = 0.f;
#pragma unroll
    for (int t = 0; t < T_; ++t) s += logits[(t*B_ + b)*OUT_ + o];
    dout[idx] = s * (1.f/32.f);
  } else {
    if (tid == 0) {
      dout[OFF_SR]     = (float)cnts[321] * (1.f/67108864.f);   // T*B*32*32*64
      dout[OFF_SR + 1] = (float)cnts[322] * (1.f/134217728.f);  // T*B*64*64*32
      dout[OFF_ACTIVE] = (float)cnts[0]   * (1.f/33554432.f);   // T*B*H*W*C
    }
    dout[OFF_ROUTE + tid] = (float)cnts[1 + tid] * (1.f/1024.f);
    if (tid < 64) dout[OFF_CHAN + tid] = (float)cnts[257 + tid] * (1.f/1024.f);
  }
}

extern "C" void kernel_launch(void* const* d_in, const int* in_sizes, int n_in,
                              void* d_out, int out_size, void* d_ws, size_t ws_size,
                              hipStream_t stream) {
  const float* x       = (const float*)d_in[0];
  const float* wf      = (const float*)d_in[1];
  const float* wp      = (const float*)d_in[2];
  const float* head_w  = (const float*)d_in[3];
  const float* head_b  = (const float*)d_in[4];
  const float* route_w = (const float*)d_in[5];
  const float* route_b = (const float*)d_in[6];
  float* out = (float*)d_out;

  float*         ws_P      = (float*)d_ws;                    // 1024*8976 floats (36.8 MB)
  float*         ws_scores = ws_P + (size_t)1024*PTB;         // 262144 floats
  float*         ws_gate   = ws_scores + T_*B_*NP_;           // 65536 floats
  int2*          ws_yx     = (int2*)(ws_gate + T_*B_*CF_);    // 1024 int2
  unsigned char* fov_part  = (unsigned char*)(ws_yx + T_*B_); // 16*32*32*2*4*32 = 4.2 MB
  unsigned char* per_part  = fov_part + (size_t)16*32*8192;   // 16*32*64*2*4*32 = 8.4 MB
  unsigned*      ws_cnt    = (unsigned*)(per_part + (size_t)16*32*16384);

  hipMemsetAsync(ws_cnt, 0, CNT_N*sizeof(unsigned), stream);

  k_pre   <<<T_*B_*4, 256, 0, stream>>>(x, ws_scores, ws_P, ws_cnt);
  k_gate  <<<T_*B_,   512, 0, stream>>>(x, ws_scores, wf, ws_yx, ws_gate,
                                        ws_cnt + 1, ws_cnt + 257);
  k_mem   <<<6144,    256, 0, stream>>>(x, ws_P, wf, wp, ws_yx, ws_gate,
                                        fov_part, per_part);
  k_logits<<<T_*B_,   256, 0, stream>>>(ws_scores, fov_part, per_part, head_w, head_b,
                                        route_w, route_b, out + OFF_LOGITS, ws_cnt + 321);
  k_final <<<17, 256, 0, stream>>>(out + OFF_LOGITS, out, ws_cnt);
}

// Round 6
// 463.979 us; speedup vs baseline: 3.5782x; 1.1772x over previous
//
#include <hip/hip_runtime.h>

#define T_ 32
#define B_ 32
#define H_ 128
#define W_ 128
#define C_ 2
#define NP_ 256
#define CF_ 64
#define CP_ 32
#define OUT_ 128

// padded periph image: rows -1..64 (66), px -2..65 (68) * 2ch = 136 floats/row
#define PROW 136
#define PTB  8976    // 66*136 floats per (t,b)
// padded fovea window: 34 rows x 34 px x 2ch = 2312 floats per (t,b)
#define WTB  2312

// d_out layout (floats): out(4096) | logits_seq(131072) | sr(2) | active(1) | route(256) | chan(64)
#define OFF_LOGITS 4096
#define OFF_SR     135168
#define OFF_ACTIVE 135170
#define OFF_ROUTE  135171
#define OFF_CHAN   135427

// ws_cnt layout (u32): [0]=active  [1..256]=route  [257..320]=chan  [321]=totf  [322]=totp
#define CNT_N 323

__device__ __forceinline__ float f4c(const float4& v, int i) {
  switch (i & 3) { case 0: return v.x; case 1: return v.y; case 2: return v.z; default: return v.w; }
}

// ---------------- K1: masked stage + patch scores + event count + padded downsample ----------------
__global__ void __launch_bounds__(256) k_pre(const float* __restrict__ x,
    float* __restrict__ scores, float* __restrict__ P, unsigned* __restrict__ active_count) {
  const int blk = blockIdx.x, tb = blk >> 2, chunk = blk & 3;
  const int r0 = chunk * 16;           // periph rows r0..r0+15
  const int tid = threadIdx.x;
  __shared__ float xt[34*256];         // masked raw rows 2r0-1 .. 2r0+32
  __shared__ unsigned wsum[4];
  const float* img = x + (size_t)tb * 32768;
  unsigned cnt = 0;
  for (int i4 = tid; i4 < 34*64; i4 += 256) {
    const int rr = i4 >> 6, off4 = i4 & 63;
    const int xr = 2*r0 - 1 + rr;
    float4 vv = make_float4(0.f, 0.f, 0.f, 0.f);
    if (xr >= 0 && xr < H_) {
      vv = *reinterpret_cast<const float4*>(img + (size_t)xr*256 + off4*4);
      if (rr >= 1 && rr <= 32) {
        cnt += (fabsf(vv.x) > 0.5f) + (fabsf(vv.y) > 0.5f)
             + (fabsf(vv.z) > 0.5f) + (fabsf(vv.w) > 0.5f);
      }
      vv.x = (fabsf(vv.x) > 0.5f) ? vv.x : 0.f;
      vv.y = (fabsf(vv.y) > 0.5f) ? vv.y : 0.f;
      vv.z = (fabsf(vv.z) > 0.5f) ? vv.z : 0.f;
      vv.w = (fabsf(vv.w) > 0.5f) ? vv.w : 0.f;
    }
    *reinterpret_cast<float4*>(&xt[i4*4]) = vv;
  }
  unsigned c64 = cnt;
#pragma unroll
  for (int off = 32; off > 0; off >>= 1) c64 += __shfl_down(c64, off);
  if ((tid & 63) == 0) wsum[tid >> 6] = c64;
  __syncthreads();
  if (tid == 0) atomicAdd(active_count, wsum[0] + wsum[1] + wsum[2] + wsum[3]);
  // ---- patch scores: 64 patches (4 patch-rows x 16), 4 threads/patch ----
  {
    const int patch = tid >> 2, q = tid & 3;
    const int prl = patch >> 4, pc = patch & 15;
    const int row = 1 + prl*8 + q*2;
    float s = 0.f;
#pragma unroll
    for (int r2 = 0; r2 < 2; ++r2)
#pragma unroll
      for (int j = 0; j < 4; ++j) {
        const float4 vv = *reinterpret_cast<const float4*>(&xt[(row + r2)*256 + pc*16 + j*4]);
        s += fabsf(vv.x) + fabsf(vv.y) + fabsf(vv.z) + fabsf(vv.w);
      }
    s += __shfl_down(s, 1);
    s += __shfl_down(s, 2);
    if (q == 0) scores[tb*NP_ + chunk*64 + patch] = s * (1.f/128.f);
  }
  // ---- padded downsample ----
  float* Pt = P + (size_t)tb * PTB;
  if (tid < 128) {                     // zero col pads (px -2,-1,64,65) for our 16 rows
    const int r = tid >> 3, rem = tid & 7;
    const int px4 = rem >> 1, ci = rem & 1;
    const int px = (px4 < 2) ? (px4 - 2) : (62 + px4);
    Pt[(r0 + r + 1)*PROW + (px + 2)*2 + ci] = 0.f;
  }
  if (chunk == 0 && tid < PROW) Pt[tid] = 0.f;            // pad row -1
  if (chunk == 3 && tid < PROW) Pt[65*PROW + tid] = 0.f;  // pad row 64
#pragma unroll
  for (int k = 0; k < 8; ++k) {
    const int idx = k*256 + tid;       // (row16*64+col)*2+ci
    const int ci = idx & 1, rest = idx >> 1;
    const int col = rest & 63, row16 = rest >> 6;
    const int pr = r0 + row16;
    float wy0=0.125f, wy1=0.375f, wy2=0.375f, wy3=0.125f;
    if (pr == 0)       { wy0=0.f;     wy1=3.f/7.f; wy2=3.f/7.f; wy3=1.f/7.f; }
    else if (pr == 63) { wy0=1.f/7.f; wy1=3.f/7.f; wy2=3.f/7.f; wy3=0.f; }
    float wx0=0.125f, wx1=0.375f, wx2=0.375f, wx3=0.125f;
    if (col == 0)       { wx0=0.f;     wx1=3.f/7.f; wx2=3.f/7.f; wx3=1.f/7.f; }
    else if (col == 63) { wx0=1.f/7.f; wx1=3.f/7.f; wx2=3.f/7.f; wx3=0.f; }
    const int lr = 2*row16;            // xt row of tap j=0
    const int cc0 = 2*col - 1;
    float val = 0.f;
#pragma unroll
    for (int j = 0; j < 4; ++j) {
      const float wyj = (j==0)?wy0:(j==1)?wy1:(j==2)?wy2:wy3;
      float h = 0.f;
#pragma unroll
      for (int i = 0; i < 4; ++i) {
        const float wxi = (i==0)?wx0:(i==1)?wx1:(i==2)?wx2:wx3;
        int cc = cc0 + i; cc = cc < 0 ? 0 : (cc > W_-1 ? W_-1 : cc);
        h += wxi * xt[(lr + j)*256 + cc*2 + ci];
      }
      val += wyj * h;
    }
    Pt[(pr + 1)*PROW + (col + 2)*2 + ci] = val;
  }
}

// ---------------- K2: rank+argmax, window dump, fovea conv -> saliency -> channel gate ----------------
__global__ void __launch_bounds__(512) k_gate(const float* __restrict__ x,
    const float* __restrict__ scores, const float* __restrict__ wf,
    float* __restrict__ Wfbuf, float* __restrict__ chan_gate,
    unsigned* __restrict__ route_count, unsigned* __restrict__ chan_count) {
  const int tb = blockIdx.x, tid = threadIdx.x;
  __shared__ float sm[NP_];
  __shared__ __align__(16) float tile[34*68];   // [34 rows][34 px * 2ch], zero-padded
  __shared__ float salred[512];
  __shared__ float salv[64];
  __shared__ int2 syx;
  if (tid < 256) sm[tid] = scores[tb*NP_ + tid];
  __syncthreads();
  if (tid < 256) {
    const float v = sm[tid];
    int cg = 0, eqb = 0;
    for (int q = 0; q < NP_; ++q) {
      cg  += (sm[q] > v) ? 1 : 0;
      eqb += ((sm[q] == v) && (q < tid)) ? 1 : 0;
    }
    if (cg < 4) atomicAdd(&route_count[tid], 1u);
    if (cg == 0 && eqb == 0) {
      const int cy = (tid >> 4)*8 + 4, cx = (tid & 15)*8 + 4;
      int y0 = cy - 16; y0 = y0 < 0 ? 0 : (y0 > 96 ? 96 : y0);
      int x0 = cx - 16; x0 = x0 < 0 ? 0 : (x0 > 96 ? 96 : x0);
      syx = make_int2(y0, x0);
    }
  }
  for (int i = tid; i < 34*68; i += 512) tile[i] = 0.f;
  __syncthreads();
  const int2 yx = syx;
  {                                    // fill interior: 32 rows x 16 segs x 2px
    const int row = tid >> 4, seg = tid & 15;
    const float* src = x + (size_t)tb*32768 + (size_t)(yx.x + row)*256 + (yx.y + seg*2)*2;
    float2 a = *reinterpret_cast<const float2*>(src);
    float2 bq = *reinterpret_cast<const float2*>(src + 2);
    a.x  = (fabsf(a.x)  > 0.5f) ? a.x  : 0.f;
    a.y  = (fabsf(a.y)  > 0.5f) ? a.y  : 0.f;
    bq.x = (fabsf(bq.x) > 0.5f) ? bq.x : 0.f;
    bq.y = (fabsf(bq.y) > 0.5f) ? bq.y : 0.f;
    float* dst = &tile[(row + 1)*68 + (seg*2 + 1)*2];
    *reinterpret_cast<float2*>(dst)     = a;
    *reinterpret_cast<float2*>(dst + 2) = bq;
  }
  __syncthreads();
  {                                    // dump padded masked window for k_mem
    float* dst = Wfbuf + (size_t)tb*WTB;
    for (int i = tid; i < WTB/4; i += 512)
      *reinterpret_cast<float4*>(dst + i*4) = *reinterpret_cast<const float4*>(&tile[i*4]);
  }
  const int c = tid & 63, grp = tid >> 6, xg = grp & 3, rh = grp >> 2;
  float wreg[18];
#pragma unroll
  for (int k = 0; k < 18; ++k) wreg[k] = wf[k*CF_ + c];
  const float* tbase = &tile[(rh*16)*68 + xg*16];
  float4 wb[3][5];
#pragma unroll
  for (int m = 0; m < 5; ++m) {
    wb[0][m] = *reinterpret_cast<const float4*>(tbase + m*4);
    wb[1][m] = *reinterpret_cast<const float4*>(tbase + 68 + m*4);
  }
  float sal = 0.f;
#pragma unroll
  for (int yy = 0; yy < 16; ++yy) {
#pragma unroll
    for (int m = 0; m < 5; ++m)
      wb[(yy+2)%3][m] = *reinterpret_cast<const float4*>(tbase + (yy+2)*68 + m*4);
#pragma unroll
    for (int k = 0; k < 8; ++k) {
      float acc = 0.f;
#pragma unroll
      for (int dy = 0; dy < 3; ++dy) {
#pragma unroll
        for (int dx = 0; dx < 3; ++dx) {
          const int r = k + dx;
          const float4 f = wb[(yy+dy)%3][r >> 1];
          acc += f4c(f, (r&1)*2)     * wreg[(dy*3+dx)*2]
               + f4c(f, (r&1)*2 + 1) * wreg[(dy*3+dx)*2 + 1];
        }
      }
      sal += fabsf(acc);
    }
  }
  salred[grp*64 + c] = sal;
  __syncthreads();
  if (tid < 64) {
    float s = 0.f;
#pragma unroll
    for (int g = 0; g < 8; ++g) s += salred[g*64 + tid];
    salv[tid] = s * (1.f/1024.f);
  }
  __syncthreads();
  if (tid < 64) {
    const float sv = salv[tid];
    int cg = 0;
    for (int q = 0; q < 64; ++q) cg += (salv[q] > sv) ? 1 : 0;
    const float gate = (cg < 16) ? 1.f : 0.f;
    chan_gate[tb*CF_ + tid] = gate;
    if (gate > 0.f) atomicAdd(&chan_count[tid], 1u);
  }
}

// ---------------- K3: persistent membranes, px-on-lanes, 2 ch/thread, no masking ----------------
// fovea:  blocks 0..4095    = b*128 + cp*4 + pq   (cp 0..31 ch-pair, pq 0..3)
//         wave w covers rows pq*8+w*2 .. +1, lane l: row += l>>5, px = l&31
// periph: blocks 4096..12287 = 4096 + b*256 + cp*16 + rq  (cp 0..15, rq 0..15)
//         wave w covers row rq*4+w, lane l: px = l
// fov_part: u32 [t][b][cp32][pw16]   per_part: u32 [t][b][cp16][row64]
__global__ void __launch_bounds__(256, 4) k_mem(const float* __restrict__ Wfbuf,
    const float* __restrict__ P, const float* __restrict__ wf, const float* __restrict__ wp,
    const float* __restrict__ chan_gate,
    unsigned* __restrict__ fov_part, unsigned* __restrict__ per_part) {
  const int tid = threadIdx.x;
  const int w = tid >> 6, l = tid & 63;
  if (blockIdx.x < 4096) {
    const int blk = blockIdx.x;
    const int b = blk >> 7, rem = blk & 127, cp = rem >> 2, pq = rem & 3;
    const int ch0 = cp*2;
    const int row = pq*8 + w*2 + (l >> 5), px = l & 31;
    float wreg[36];
#pragma unroll
    for (int k = 0; k < 18; ++k) {
      wreg[k]      = wf[k*CF_ + ch0];
      wreg[18 + k] = wf[k*CF_ + ch0 + 1];
    }
    float v0 = 0.f, v1 = 0.f;
    for (int t = 0; t < T_; ++t) {
      const int tb = t*B_ + b;
      const float* base = Wfbuf + (size_t)tb*WTB + (size_t)row*68 + px*2;
      float acc0 = 0.f, acc1 = 0.f;
#pragma unroll
      for (int dy = 0; dy < 3; ++dy)
#pragma unroll
        for (int dx = 0; dx < 3; ++dx) {
          const float2 f = *reinterpret_cast<const float2*>(base + dy*68 + dx*2);
          acc0 += f.x*wreg[(dy*3+dx)*2]      + f.y*wreg[(dy*3+dx)*2 + 1];
          acc1 += f.x*wreg[18+(dy*3+dx)*2]   + f.y*wreg[18+(dy*3+dx)*2 + 1];
        }
      const float g0 = chan_gate[tb*CF_ + ch0];
      const float g1 = chan_gate[tb*CF_ + ch0 + 1];
      float nv0 = 0.9f*v0 + acc0*g0;
      float nv1 = 0.9f*v1 + acc1*g1;
      unsigned packed = 0;
      if (nv0 > 1.0f) { nv0 -= 1.0f; packed += 1u; }
      if (nv1 > 1.0f) { nv1 -= 1.0f; packed += (1u << 16); }
      v0 = nv0; v1 = nv1;
#pragma unroll
      for (int off = 32; off > 0; off >>= 1) packed += __shfl_down(packed, off);
      if (l == 0) fov_part[(((size_t)t*B_ + b)*32 + cp)*16 + pq*4 + w] = packed;
    }
  } else {
    const int blk = blockIdx.x - 4096;
    const int b = blk >> 8, rem = blk & 255, cp = rem >> 4, rq = rem & 15;
    const int ch0 = cp*2;
    const int row = rq*4 + w, px = l;
    float wreg[36];
#pragma unroll
    for (int k = 0; k < 18; ++k) {
      wreg[k]      = wp[k*CP_ + ch0];
      wreg[18 + k] = wp[k*CP_ + ch0 + 1];
    }
    float v0 = 0.f, v1 = 0.f;
    for (int t = 0; t < T_; ++t) {
      const int tb = t*B_ + b;
      const float* base = P + (size_t)tb*PTB + (size_t)row*PROW + (px + 1)*2;
      float acc0 = 0.f, acc1 = 0.f;
#pragma unroll
      for (int dy = 0; dy < 3; ++dy)
#pragma unroll
        for (int dx = 0; dx < 3; ++dx) {
          const float2 f = *reinterpret_cast<const float2*>(base + dy*PROW + dx*2);
          acc0 += f.x*wreg[(dy*3+dx)*2]      + f.y*wreg[(dy*3+dx)*2 + 1];
          acc1 += f.x*wreg[18+(dy*3+dx)*2]   + f.y*wreg[18+(dy*3+dx)*2 + 1];
        }
      float nv0 = 0.9f*v0 + acc0;
      float nv1 = 0.9f*v1 + acc1;
      unsigned packed = 0;
      if (nv0 > 1.0f) { nv0 -= 1.0f; packed += 1u; }
      if (nv1 > 1.0f) { nv1 -= 1.0f; packed += (1u << 16); }
      v0 = nv0; v1 = nv1;
#pragma unroll
      for (int off = 32; off > 0; off >>= 1) packed += __shfl_down(packed, off);
      if (l == 0) per_part[(((size_t)t*B_ + b)*16 + cp)*64 + rq*4 + w] = packed;
    }
  }
}

// ---------------- K4: reduce partials + logits ----------------
__global__ void __launch_bounds__(256) k_logits(const float* __restrict__ scores,
    const unsigned* __restrict__ fov_part, const unsigned* __restrict__ per_part,
    const float* __restrict__ head_w, const float* __restrict__ head_b,
    const float* __restrict__ route_w, const float* __restrict__ route_b,
    float* __restrict__ logits, unsigned* __restrict__ tot) {
  const int tb = blockIdx.x, tid = threadIdx.x;
  __shared__ float sc[NP_];
  __shared__ float fu[96];
  sc[tid] = scores[tb*NP_ + tid];
  if (tid < 64) {
    const unsigned* fp = fov_part + (size_t)tb*512;   // 32 cp * 16 pw
    const int cp = tid >> 1, sh = (tid & 1)*16;
    unsigned fsum = 0;
#pragma unroll
    for (int pw = 0; pw < 16; ++pw) fsum += (fp[cp*16 + pw] >> sh) & 0xFFFFu;
    fu[tid] = (float)fsum * (1.f/1024.f);
    unsigned r = fsum;
#pragma unroll
    for (int off = 32; off > 0; off >>= 1) r += __shfl_down(r, off);
    if (tid == 0) atomicAdd(&tot[0], r);
  } else if (tid < 128) {
    const int c = tid - 64;            // 0..63, only c<32 active
    unsigned psum = 0;
    if (c < 32) {
      const unsigned* pp = per_part + (size_t)tb*1024;  // 16 cp * 64 rows
      const int cp = c >> 1, sh = (c & 1)*16;
#pragma unroll 8
      for (int rw = 0; rw < 64; ++rw) psum += (pp[cp*64 + rw] >> sh) & 0xFFFFu;
      fu[64 + c] = (float)psum * (1.f/4096.f);
    }
    unsigned r = psum;
#pragma unroll
    for (int off = 32; off > 0; off >>= 1) r += __shfl_down(r, off);
    if (tid == 64) atomicAdd(&tot[1], r);
  }
  __syncthreads();
  if (tid < 128) {
    const int o = tid;
    float acc = head_b[o] + route_b[o];
#pragma unroll 8
    for (int k = 0; k < 96; ++k)  acc += fu[k]*head_w[k*OUT_ + o];
#pragma unroll 8
    for (int p = 0; p < NP_; ++p) acc += sc[p]*route_w[p*OUT_ + o];
    logits[tb*OUT_ + o] = acc;
  }
}

// ---------------- K5: finalize ----------------
__global__ void __launch_bounds__(256) k_final(const float* __restrict__ logits,
    float* __restrict__ dout, const unsigned* __restrict__ cnts) {
  const int blk = blockIdx.x, tid = threadIdx.x;
  if (blk < 16) {
    const int idx = blk*256 + tid;
    const int b = idx >> 7, o = idx & 127;
    float s = 0.f;
#pragma unroll
    for (int t = 0; t < T_; ++t) s += logits[(t*B_ + b)*OUT_ + o];
    dout[idx] = s * (1.f/32.f);
  } else {
    if (tid == 0) {
      dout[OFF_SR]     = (float)cnts[321] * (1.f/67108864.f);   // T*B*32*32*64
      dout[OFF_SR + 1] = (float)cnts[322] * (1.f/134217728.f);  // T*B*64*64*32
      dout[OFF_ACTIVE] = (float)cnts[0]   * (1.f/33554432.f);   // T*B*H*W*C
    }
    dout[OFF_ROUTE + tid] = (float)cnts[1 + tid] * (1.f/1024.f);
    if (tid < 64) dout[OFF_CHAN + tid] = (float)cnts[257 + tid] * (1.f/1024.f);
  }
}

extern "C" void kernel_launch(void* const* d_in, const int* in_sizes, int n_in,
                              void* d_out, int out_size, void* d_ws, size_t ws_size,
                              hipStream_t stream) {
  const float* x       = (const float*)d_in[0];
  const float* wf      = (const float*)d_in[1];
  const float* wp      = (const float*)d_in[2];
  const float* head_w  = (const float*)d_in[3];
  const float* head_b  = (const float*)d_in[4];
  const float* route_w = (const float*)d_in[5];
  const float* route_b = (const float*)d_in[6];
  float* out = (float*)d_out;

  float*    ws_P      = (float*)d_ws;                         // 1024*8976 floats (36.8 MB)
  float*    ws_Wf     = ws_P + (size_t)1024*PTB;              // 1024*2312 floats (9.5 MB)
  float*    ws_scores = ws_Wf + (size_t)1024*WTB;             // 262144 floats
  float*    ws_gate   = ws_scores + T_*B_*NP_;                // 65536 floats
  unsigned* fov_part  = (unsigned*)(ws_gate + T_*B_*CF_);     // 32*32*32*16 u32 (2 MB)
  unsigned* per_part  = fov_part + (size_t)T_*B_*512;         // 32*32*16*64 u32 (4 MB)
  unsigned* ws_cnt    = per_part + (size_t)T_*B_*1024;

  hipMemsetAsync(ws_cnt, 0, CNT_N*sizeof(unsigned), stream);

  k_pre   <<<T_*B_*4, 256, 0, stream>>>(x, ws_scores, ws_P, ws_cnt);
  k_gate  <<<T_*B_,   512, 0, stream>>>(x, ws_scores, wf, ws_Wf, ws_gate,
                                        ws_cnt + 1, ws_cnt + 257);
  k_mem   <<<12288,   256, 0, stream>>>(ws_Wf, ws_P, wf, wp, ws_gate,
                                        fov_part, per_part);
  k_logits<<<T_*B_,   256, 0, stream>>>(ws_scores, fov_part, per_part, head_w, head_b,
                                        route_w, route_b, out + OFF_LOGITS, ws_cnt + 321);
  k_final <<<17, 256, 0, stream>>>(out + OFF_LOGITS, out, ws_cnt);
}

// Round 7
// 327.228 us; speedup vs baseline: 5.0736x; 1.4179x over previous
//
#include <hip/hip_runtime.h>

#define T_ 32
#define B_ 32
#define H_ 128
#define W_ 128
#define C_ 2
#define NP_ 256
#define CF_ 64
#define CP_ 32
#define OUT_ 128

// padded periph image: rows -1..64 (66), px -2..65 (68) * 2ch = 136 floats/row
#define PROW 136
#define PTB  8976    // 66*136 floats per (t,b)
// padded fovea window: 34 rows x 34 px x 2ch = 2312 floats per (t,b)
#define WTB  2312

// d_out layout (floats): out(4096) | logits_seq(131072) | sr(2) | active(1) | route(256) | chan(64)
#define OFF_LOGITS 4096
#define OFF_SR     135168
#define OFF_ACTIVE 135170
#define OFF_ROUTE  135171
#define OFF_CHAN   135427

// ws_cnt layout (u32): [0]=active  [1..256]=route  [257..320]=chan  [321]=totf  [322]=totp
#define CNT_N 323

__device__ __forceinline__ float f4c(const float4& v, int i) {
  switch (i & 3) { case 0: return v.x; case 1: return v.y; case 2: return v.z; default: return v.w; }
}

// ---------------- K1: masked stage + patch scores + event count + padded downsample ----------------
__global__ void __launch_bounds__(256) k_pre(const float* __restrict__ x,
    float* __restrict__ scores, float* __restrict__ P, unsigned* __restrict__ active_count) {
  const int blk = blockIdx.x, tb = blk >> 2, chunk = blk & 3;
  const int r0 = chunk * 16;           // periph rows r0..r0+15
  const int tid = threadIdx.x;
  __shared__ float xt[34*256];         // masked raw rows 2r0-1 .. 2r0+32
  __shared__ unsigned wsum[4];
  const float* img = x + (size_t)tb * 32768;
  unsigned cnt = 0;
  for (int i4 = tid; i4 < 34*64; i4 += 256) {
    const int rr = i4 >> 6, off4 = i4 & 63;
    const int xr = 2*r0 - 1 + rr;
    float4 vv = make_float4(0.f, 0.f, 0.f, 0.f);
    if (xr >= 0 && xr < H_) {
      vv = *reinterpret_cast<const float4*>(img + (size_t)xr*256 + off4*4);
      if (rr >= 1 && rr <= 32) {
        cnt += (fabsf(vv.x) > 0.5f) + (fabsf(vv.y) > 0.5f)
             + (fabsf(vv.z) > 0.5f) + (fabsf(vv.w) > 0.5f);
      }
      vv.x = (fabsf(vv.x) > 0.5f) ? vv.x : 0.f;
      vv.y = (fabsf(vv.y) > 0.5f) ? vv.y : 0.f;
      vv.z = (fabsf(vv.z) > 0.5f) ? vv.z : 0.f;
      vv.w = (fabsf(vv.w) > 0.5f) ? vv.w : 0.f;
    }
    *reinterpret_cast<float4*>(&xt[i4*4]) = vv;
  }
  unsigned c64 = cnt;
#pragma unroll
  for (int off = 32; off > 0; off >>= 1) c64 += __shfl_down(c64, off);
  if ((tid & 63) == 0) wsum[tid >> 6] = c64;
  __syncthreads();
  if (tid == 0) atomicAdd(active_count, wsum[0] + wsum[1] + wsum[2] + wsum[3]);
  // ---- patch scores: 64 patches (4 patch-rows x 16), 4 threads/patch ----
  {
    const int patch = tid >> 2, q = tid & 3;
    const int prl = patch >> 4, pc = patch & 15;
    const int row = 1 + prl*8 + q*2;
    float s = 0.f;
#pragma unroll
    for (int r2 = 0; r2 < 2; ++r2)
#pragma unroll
      for (int j = 0; j < 4; ++j) {
        const float4 vv = *reinterpret_cast<const float4*>(&xt[(row + r2)*256 + pc*16 + j*4]);
        s += fabsf(vv.x) + fabsf(vv.y) + fabsf(vv.z) + fabsf(vv.w);
      }
    s += __shfl_down(s, 1);
    s += __shfl_down(s, 2);
    if (q == 0) scores[tb*NP_ + chunk*64 + patch] = s * (1.f/128.f);
  }
  // ---- padded downsample ----
  float* Pt = P + (size_t)tb * PTB;
  if (tid < 128) {                     // zero col pads (px -2,-1,64,65) for our 16 rows
    const int r = tid >> 3, rem = tid & 7;
    const int px4 = rem >> 1, ci = rem & 1;
    const int px = (px4 < 2) ? (px4 - 2) : (62 + px4);
    Pt[(r0 + r + 1)*PROW + (px + 2)*2 + ci] = 0.f;
  }
  if (chunk == 0 && tid < PROW) Pt[tid] = 0.f;            // pad row -1
  if (chunk == 3 && tid < PROW) Pt[65*PROW + tid] = 0.f;  // pad row 64
#pragma unroll
  for (int k = 0; k < 8; ++k) {
    const int idx = k*256 + tid;       // (row16*64+col)*2+ci
    const int ci = idx & 1, rest = idx >> 1;
    const int col = rest & 63, row16 = rest >> 6;
    const int pr = r0 + row16;
    float wy0=0.125f, wy1=0.375f, wy2=0.375f, wy3=0.125f;
    if (pr == 0)       { wy0=0.f;     wy1=3.f/7.f; wy2=3.f/7.f; wy3=1.f/7.f; }
    else if (pr == 63) { wy0=1.f/7.f; wy1=3.f/7.f; wy2=3.f/7.f; wy3=0.f; }
    float wx0=0.125f, wx1=0.375f, wx2=0.375f, wx3=0.125f;
    if (col == 0)       { wx0=0.f;     wx1=3.f/7.f; wx2=3.f/7.f; wx3=1.f/7.f; }
    else if (col == 63) { wx0=1.f/7.f; wx1=3.f/7.f; wx2=3.f/7.f; wx3=0.f; }
    const int lr = 2*row16;            // xt row of tap j=0
    const int cc0 = 2*col - 1;
    float val = 0.f;
#pragma unroll
    for (int j = 0; j < 4; ++j) {
      const float wyj = (j==0)?wy0:(j==1)?wy1:(j==2)?wy2:wy3;
      float h = 0.f;
#pragma unroll
      for (int i = 0; i < 4; ++i) {
        const float wxi = (i==0)?wx0:(i==1)?wx1:(i==2)?wx2:wx3;
        int cc = cc0 + i; cc = cc < 0 ? 0 : (cc > W_-1 ? W_-1 : cc);
        h += wxi * xt[(lr + j)*256 + cc*2 + ci];
      }
      val += wyj * h;
    }
    Pt[(pr + 1)*PROW + (col + 2)*2 + ci] = val;
  }
}

// ---------------- K2: rank+argmax, window dump, fovea conv -> saliency -> channel gate ----------------
__global__ void __launch_bounds__(512) k_gate(const float* __restrict__ x,
    const float* __restrict__ scores, const float* __restrict__ wf,
    float* __restrict__ Wfbuf, float* __restrict__ chan_gate,
    unsigned* __restrict__ route_count, unsigned* __restrict__ chan_count) {
  const int tb = blockIdx.x, tid = threadIdx.x;
  __shared__ float sm[NP_];
  __shared__ __align__(16) float tile[34*68];   // [34 rows][34 px * 2ch], zero-padded
  __shared__ float salred[512];
  __shared__ float salv[64];
  __shared__ int2 syx;
  if (tid < 256) sm[tid] = scores[tb*NP_ + tid];
  __syncthreads();
  if (tid < 256) {
    const float v = sm[tid];
    int cg = 0, eqb = 0;
    for (int q = 0; q < NP_; ++q) {
      cg  += (sm[q] > v) ? 1 : 0;
      eqb += ((sm[q] == v) && (q < tid)) ? 1 : 0;
    }
    if (cg < 4) atomicAdd(&route_count[tid], 1u);
    if (cg == 0 && eqb == 0) {
      const int cy = (tid >> 4)*8 + 4, cx = (tid & 15)*8 + 4;
      int y0 = cy - 16; y0 = y0 < 0 ? 0 : (y0 > 96 ? 96 : y0);
      int x0 = cx - 16; x0 = x0 < 0 ? 0 : (x0 > 96 ? 96 : x0);
      syx = make_int2(y0, x0);
    }
  }
  for (int i = tid; i < 34*68; i += 512) tile[i] = 0.f;
  __syncthreads();
  const int2 yx = syx;
  {                                    // fill interior: 32 rows x 16 segs x 2px
    const int row = tid >> 4, seg = tid & 15;
    const float* src = x + (size_t)tb*32768 + (size_t)(yx.x + row)*256 + (yx.y + seg*2)*2;
    float2 a = *reinterpret_cast<const float2*>(src);
    float2 bq = *reinterpret_cast<const float2*>(src + 2);
    a.x  = (fabsf(a.x)  > 0.5f) ? a.x  : 0.f;
    a.y  = (fabsf(a.y)  > 0.5f) ? a.y  : 0.f;
    bq.x = (fabsf(bq.x) > 0.5f) ? bq.x : 0.f;
    bq.y = (fabsf(bq.y) > 0.5f) ? bq.y : 0.f;
    float* dst = &tile[(row + 1)*68 + (seg*2 + 1)*2];
    *reinterpret_cast<float2*>(dst)     = a;
    *reinterpret_cast<float2*>(dst + 2) = bq;
  }
  __syncthreads();
  {                                    // dump padded masked window for k_mem
    float* dst = Wfbuf + (size_t)tb*WTB;
    for (int i = tid; i < WTB/4; i += 512)
      *reinterpret_cast<float4*>(dst + i*4) = *reinterpret_cast<const float4*>(&tile[i*4]);
  }
  const int c = tid & 63, grp = tid >> 6, xg = grp & 3, rh = grp >> 2;
  float wreg[18];
#pragma unroll
  for (int k = 0; k < 18; ++k) wreg[k] = wf[k*CF_ + c];
  const float* tbase = &tile[(rh*16)*68 + xg*16];
  float4 wb[3][5];
#pragma unroll
  for (int m = 0; m < 5; ++m) {
    wb[0][m] = *reinterpret_cast<const float4*>(tbase + m*4);
    wb[1][m] = *reinterpret_cast<const float4*>(tbase + 68 + m*4);
  }
  float sal = 0.f;
#pragma unroll
  for (int yy = 0; yy < 16; ++yy) {
#pragma unroll
    for (int m = 0; m < 5; ++m)
      wb[(yy+2)%3][m] = *reinterpret_cast<const float4*>(tbase + (yy+2)*68 + m*4);
#pragma unroll
    for (int k = 0; k < 8; ++k) {
      float acc = 0.f;
#pragma unroll
      for (int dy = 0; dy < 3; ++dy) {
#pragma unroll
        for (int dx = 0; dx < 3; ++dx) {
          const int r = k + dx;
          const float4 f = wb[(yy+dy)%3][r >> 1];
          acc += f4c(f, (r&1)*2)     * wreg[(dy*3+dx)*2]
               + f4c(f, (r&1)*2 + 1) * wreg[(dy*3+dx)*2 + 1];
        }
      }
      sal += fabsf(acc);
    }
  }
  salred[grp*64 + c] = sal;
  __syncthreads();
  if (tid < 64) {
    float s = 0.f;
#pragma unroll
    for (int g = 0; g < 8; ++g) s += salred[g*64 + tid];
    salv[tid] = s * (1.f/1024.f);
  }
  __syncthreads();
  if (tid < 64) {
    const float sv = salv[tid];
    int cg = 0;
    for (int q = 0; q < 64; ++q) cg += (salv[q] > sv) ? 1 : 0;
    const float gate = (cg < 16) ? 1.f : 0.f;
    chan_gate[tb*CF_ + tid] = gate;
    if (gate > 0.f) atomicAdd(&chan_count[tid], 1u);
  }
}

// ---------------- K3: persistent membranes, 2px/lane, ballot spike counting ----------------
// fovea:  blocks 0..2047  = b*64 + cp*2 + half ; wave w: rows half*16+w*4 .. +3
//         lane l: row += l>>4, px0 = (l&15)*2
// periph: blocks 2048..6143 = 2048 + b*128 + cp*8 + rq ; wave w: rows rq*8+w*2 .. +1
//         lane l: row += l>>5, px0 = (l&31)*2
// fov_part: u32 [t][b][cp32][8]  (cnt0 | cnt1<<16)
// per_part: u32 [t][b][cp16][32]
__global__ void __launch_bounds__(256, 4) k_mem(const float* __restrict__ Wfbuf,
    const float* __restrict__ P, const float* __restrict__ wf, const float* __restrict__ wp,
    const float* __restrict__ chan_gate,
    unsigned* __restrict__ fov_part, unsigned* __restrict__ per_part) {
  const int tid = threadIdx.x;
  const int w = tid >> 6, l = tid & 63;
  if (blockIdx.x < 2048) {
    const int blk = blockIdx.x;
    const int b = blk >> 6, rem = blk & 63, cp = rem >> 1, half = rem & 1;
    const int ch0 = cp*2;
    const int row = half*16 + w*4 + (l >> 4);
    const int px0 = (l & 15)*2;
    float wr0[18], wr1[18];
#pragma unroll
    for (int k = 0; k < 18; ++k) {
      wr0[k] = wf[k*CF_ + ch0];
      wr1[k] = wf[k*CF_ + ch0 + 1];
    }
    float v0a = 0.f, v0b = 0.f, v1a = 0.f, v1b = 0.f;
    for (int t = 0; t < T_; ++t) {
      const int tb = t*B_ + b;
      const float* base = Wfbuf + (size_t)tb*WTB + (size_t)row*68 + px0*2;
      float a0a = 0.f, a0b = 0.f, a1a = 0.f, a1b = 0.f;
#pragma unroll
      for (int dy = 0; dy < 3; ++dy) {
        const float4 fa = *reinterpret_cast<const float4*>(base + dy*68);
        const float4 fb = *reinterpret_cast<const float4*>(base + dy*68 + 4);
        const float cx[4] = {fa.x, fa.z, fb.x, fb.z};
        const float cy[4] = {fa.y, fa.w, fb.y, fb.w};
#pragma unroll
        for (int dx = 0; dx < 3; ++dx) {
          const float w0x = wr0[dy*6 + dx*2], w0y = wr0[dy*6 + dx*2 + 1];
          const float w1x = wr1[dy*6 + dx*2], w1y = wr1[dy*6 + dx*2 + 1];
          a0a += cx[dx]*w0x     + cy[dx]*w0y;
          a0b += cx[dx+1]*w0x   + cy[dx+1]*w0y;
          a1a += cx[dx]*w1x     + cy[dx]*w1y;
          a1b += cx[dx+1]*w1x   + cy[dx+1]*w1y;
        }
      }
      const float g0 = chan_gate[tb*CF_ + ch0];
      const float g1 = chan_gate[tb*CF_ + ch0 + 1];
      float n0a = 0.9f*v0a + a0a*g0;
      float n0b = 0.9f*v0b + a0b*g0;
      float n1a = 0.9f*v1a + a1a*g1;
      float n1b = 0.9f*v1b + a1b*g1;
      const bool s0a = n0a > 1.f, s0b = n0b > 1.f, s1a = n1a > 1.f, s1b = n1b > 1.f;
      v0a = s0a ? n0a - 1.f : n0a;
      v0b = s0b ? n0b - 1.f : n0b;
      v1a = s1a ? n1a - 1.f : n1a;
      v1b = s1b ? n1b - 1.f : n1b;
      const unsigned long long m0a = __ballot(s0a), m0b = __ballot(s0b);
      const unsigned long long m1a = __ballot(s1a), m1b = __ballot(s1b);
      const unsigned packed = (unsigned)(__popcll(m0a) + __popcll(m0b))
                            | ((unsigned)(__popcll(m1a) + __popcll(m1b)) << 16);
      if (l == 0) fov_part[((size_t)tb*32 + cp)*8 + half*4 + w] = packed;
    }
  } else {
    const int blk = blockIdx.x - 2048;
    const int b = blk >> 7, rem = blk & 127, cp = rem >> 3, rq = rem & 7;
    const int ch0 = cp*2;
    const int row = rq*8 + w*2 + (l >> 5);
    const int px0 = (l & 31)*2;
    float wr0[18], wr1[18];
#pragma unroll
    for (int k = 0; k < 18; ++k) {
      wr0[k] = wp[k*CP_ + ch0];
      wr1[k] = wp[k*CP_ + ch0 + 1];
    }
    float v0a = 0.f, v0b = 0.f, v1a = 0.f, v1b = 0.f;
    for (int t = 0; t < T_; ++t) {
      const int tb = t*B_ + b;
      const float* base = P + (size_t)tb*PTB + (size_t)row*PROW + px0*2;
      float a0a = 0.f, a0b = 0.f, a1a = 0.f, a1b = 0.f;
#pragma unroll
      for (int dy = 0; dy < 3; ++dy) {
        const float4 f0 = *reinterpret_cast<const float4*>(base + dy*PROW);
        const float4 f1 = *reinterpret_cast<const float4*>(base + dy*PROW + 4);
        const float4 f2 = *reinterpret_cast<const float4*>(base + dy*PROW + 8);
        const float cx[6] = {f0.x, f0.z, f1.x, f1.z, f2.x, f2.z};
        const float cy[6] = {f0.y, f0.w, f1.y, f1.w, f2.y, f2.w};
#pragma unroll
        for (int dx = 0; dx < 3; ++dx) {
          const float w0x = wr0[dy*6 + dx*2], w0y = wr0[dy*6 + dx*2 + 1];
          const float w1x = wr1[dy*6 + dx*2], w1y = wr1[dy*6 + dx*2 + 1];
          a0a += cx[dx+1]*w0x   + cy[dx+1]*w0y;
          a0b += cx[dx+2]*w0x   + cy[dx+2]*w0y;
          a1a += cx[dx+1]*w1x   + cy[dx+1]*w1y;
          a1b += cx[dx+2]*w1x   + cy[dx+2]*w1y;
        }
      }
      float n0a = 0.9f*v0a + a0a;
      float n0b = 0.9f*v0b + a0b;
      float n1a = 0.9f*v1a + a1a;
      float n1b = 0.9f*v1b + a1b;
      const bool s0a = n0a > 1.f, s0b = n0b > 1.f, s1a = n1a > 1.f, s1b = n1b > 1.f;
      v0a = s0a ? n0a - 1.f : n0a;
      v0b = s0b ? n0b - 1.f : n0b;
      v1a = s1a ? n1a - 1.f : n1a;
      v1b = s1b ? n1b - 1.f : n1b;
      const unsigned long long m0a = __ballot(s0a), m0b = __ballot(s0b);
      const unsigned long long m1a = __ballot(s1a), m1b = __ballot(s1b);
      const unsigned packed = (unsigned)(__popcll(m0a) + __popcll(m0b))
                            | ((unsigned)(__popcll(m1a) + __popcll(m1b)) << 16);
      if (l == 0) per_part[((size_t)tb*16 + cp)*32 + rq*4 + w] = packed;
    }
  }
}

// ---------------- K4: reduce partials + logits ----------------
__global__ void __launch_bounds__(256) k_logits(const float* __restrict__ scores,
    const unsigned* __restrict__ fov_part, const unsigned* __restrict__ per_part,
    const float* __restrict__ head_w, const float* __restrict__ head_b,
    const float* __restrict__ route_w, const float* __restrict__ route_b,
    float* __restrict__ logits, unsigned* __restrict__ tot) {
  const int tb = blockIdx.x, tid = threadIdx.x;
  __shared__ float sc[NP_];
  __shared__ float fu[96];
  sc[tid] = scores[tb*NP_ + tid];
  if (tid < 64) {
    const unsigned* fp = fov_part + (size_t)tb*256;   // 32 cp * 8
    const int cp = tid >> 1, sh = (tid & 1)*16;
    unsigned fsum = 0;
#pragma unroll
    for (int i = 0; i < 8; ++i) fsum += (fp[cp*8 + i] >> sh) & 0xFFFFu;
    fu[tid] = (float)fsum * (1.f/1024.f);
    unsigned r = fsum;
#pragma unroll
    for (int off = 32; off > 0; off >>= 1) r += __shfl_down(r, off);
    if (tid == 0) atomicAdd(&tot[0], r);
  } else if (tid < 128) {
    const int c = tid - 64;            // 0..63, only c<32 active
    unsigned psum = 0;
    if (c < 32) {
      const unsigned* pp = per_part + (size_t)tb*512;  // 16 cp * 32
      const int cp = c >> 1, sh = (c & 1)*16;
#pragma unroll 8
      for (int i = 0; i < 32; ++i) psum += (pp[cp*32 + i] >> sh) & 0xFFFFu;
      fu[64 + c] = (float)psum * (1.f/4096.f);
    }
    unsigned r = psum;
#pragma unroll
    for (int off = 32; off > 0; off >>= 1) r += __shfl_down(r, off);
    if (tid == 64) atomicAdd(&tot[1], r);
  }
  __syncthreads();
  if (tid < 128) {
    const int o = tid;
    float acc = head_b[o] + route_b[o];
#pragma unroll 8
    for (int k = 0; k < 96; ++k)  acc += fu[k]*head_w[k*OUT_ + o];
#pragma unroll 8
    for (int p = 0; p < NP_; ++p) acc += sc[p]*route_w[p*OUT_ + o];
    logits[tb*OUT_ + o] = acc;
  }
}

// ---------------- K5: finalize ----------------
__global__ void __launch_bounds__(256) k_final(const float* __restrict__ logits,
    float* __restrict__ dout, const unsigned* __restrict__ cnts) {
  const int blk = blockIdx.x, tid = threadIdx.x;
  if (blk < 16) {
    const int idx = blk*256 + tid;
    const int b = idx >> 7, o = idx & 127;
    float s = 0.f;
#pragma unroll
    for (int t = 0; t < T_; ++t) s += logits[(t*B_ + b)*OUT_ + o];
    dout[idx] = s * (1.f/32.f);
  } else {
    if (tid == 0) {
      dout[OFF_SR]     = (float)cnts[321] * (1.f/67108864.f);   // T*B*32*32*64
      dout[OFF_SR + 1] = (float)cnts[322] * (1.f/134217728.f);  // T*B*64*64*32
      dout[OFF_ACTIVE] = (float)cnts[0]   * (1.f/33554432.f);   // T*B*H*W*C
    }
    dout[OFF_ROUTE + tid] = (float)cnts[1 + tid] * (1.f/1024.f);
    if (tid < 64) dout[OFF_CHAN + tid] = (float)cnts[257 + tid] * (1.f/1024.f);
  }
}

extern "C" void kernel_launch(void* const* d_in, const int* in_sizes, int n_in,
                              void* d_out, int out_size, void* d_ws, size_t ws_size,
                              hipStream_t stream) {
  const float* x       = (const float*)d_in[0];
  const float* wf      = (const float*)d_in[1];
  const float* wp      = (const float*)d_in[2];
  const float* head_w  = (const float*)d_in[3];
  const float* head_b  = (const float*)d_in[4];
  const float* route_w = (const float*)d_in[5];
  const float* route_b = (const float*)d_in[6];
  float* out = (float*)d_out;

  float*    ws_P      = (float*)d_ws;                         // 1024*8976 floats (36.8 MB)
  float*    ws_Wf     = ws_P + (size_t)1024*PTB;              // 1024*2312 floats (9.5 MB)
  float*    ws_scores = ws_Wf + (size_t)1024*WTB;             // 262144 floats
  float*    ws_gate   = ws_scores + T_*B_*NP_;                // 65536 floats
  unsigned* fov_part  = (unsigned*)(ws_gate + T_*B_*CF_);     // 32*32*32*8 u32 (1 MB)
  unsigned* per_part  = fov_part + (size_t)T_*B_*256;         // 32*32*16*32 u32 (2 MB)
  unsigned* ws_cnt    = per_part + (size_t)T_*B_*512;

  hipMemsetAsync(ws_cnt, 0, CNT_N*sizeof(unsigned), stream);

  k_pre   <<<T_*B_*4, 256, 0, stream>>>(x, ws_scores, ws_P, ws_cnt);
  k_gate  <<<T_*B_,   512, 0, stream>>>(x, ws_scores, wf, ws_Wf, ws_gate,
                                        ws_cnt + 1, ws_cnt + 257);
  k_mem   <<<6144,    256, 0, stream>>>(ws_Wf, ws_P, wf, wp, ws_gate,
                                        fov_part, per_part);
  k_logits<<<T_*B_,   256, 0, stream>>>(ws_scores, fov_part, per_part, head_w, head_b,
                                        route_w, route_b, out + OFF_LOGITS, ws_cnt + 321);
  k_final <<<17, 256, 0, stream>>>(out + OFF_LOGITS, out, ws_cnt);
}

// Round 8
// 309.815 us; speedup vs baseline: 5.3587x; 1.0562x over previous
//
#include <hip/hip_runtime.h>

#define T_ 32
#define B_ 32
#define H_ 128
#define W_ 128
#define C_ 2
#define NP_ 256
#define CF_ 64
#define CP_ 32
#define OUT_ 128

// padded periph image: rows -1..64 (66), px -2..65 (68) * 2ch = 136 floats/row
#define PROW 136
#define PTB  8976    // 66*136 floats per (t,b)
// padded fovea window: 34 rows x 34 px x 2ch = 2312 floats per (t,b)
#define WTB  2312

// d_out layout (floats): out(4096) | logits_seq(131072) | sr(2) | active(1) | route(256) | chan(64)
#define OFF_LOGITS 4096
#define OFF_SR     135168
#define OFF_ACTIVE 135170
#define OFF_ROUTE  135171
#define OFF_CHAN   135427

// ws_cnt layout (u32): [0]=active  [1..256]=route  [257..320]=chan  [321]=totf  [322]=totp
#define CNT_N 323

typedef float f2 __attribute__((ext_vector_type(2)));

__device__ __forceinline__ float f4c(const float4& v, int i) {
  switch (i & 3) { case 0: return v.x; case 1: return v.y; case 2: return v.z; default: return v.w; }
}

// ---------------- K1: masked stage + patch scores + event count + padded downsample ----------------
__global__ void __launch_bounds__(256) k_pre(const float* __restrict__ x,
    float* __restrict__ scores, float* __restrict__ P, unsigned* __restrict__ active_count) {
  const int blk = blockIdx.x, tb = blk >> 2, chunk = blk & 3;
  const int r0 = chunk * 16;           // periph rows r0..r0+15
  const int tid = threadIdx.x;
  __shared__ float xt[34*256];         // masked raw rows 2r0-1 .. 2r0+32
  __shared__ unsigned wsum[4];
  const float* img = x + (size_t)tb * 32768;
  unsigned cnt = 0;
  for (int i4 = tid; i4 < 34*64; i4 += 256) {
    const int rr = i4 >> 6, off4 = i4 & 63;
    const int xr = 2*r0 - 1 + rr;
    float4 vv = make_float4(0.f, 0.f, 0.f, 0.f);
    if (xr >= 0 && xr < H_) {
      vv = *reinterpret_cast<const float4*>(img + (size_t)xr*256 + off4*4);
      if (rr >= 1 && rr <= 32) {
        cnt += (fabsf(vv.x) > 0.5f) + (fabsf(vv.y) > 0.5f)
             + (fabsf(vv.z) > 0.5f) + (fabsf(vv.w) > 0.5f);
      }
      vv.x = (fabsf(vv.x) > 0.5f) ? vv.x : 0.f;
      vv.y = (fabsf(vv.y) > 0.5f) ? vv.y : 0.f;
      vv.z = (fabsf(vv.z) > 0.5f) ? vv.z : 0.f;
      vv.w = (fabsf(vv.w) > 0.5f) ? vv.w : 0.f;
    }
    *reinterpret_cast<float4*>(&xt[i4*4]) = vv;
  }
  unsigned c64 = cnt;
#pragma unroll
  for (int off = 32; off > 0; off >>= 1) c64 += __shfl_down(c64, off);
  if ((tid & 63) == 0) wsum[tid >> 6] = c64;
  __syncthreads();
  if (tid == 0) atomicAdd(active_count, wsum[0] + wsum[1] + wsum[2] + wsum[3]);
  // ---- patch scores: 64 patches (4 patch-rows x 16), 4 threads/patch ----
  {
    const int patch = tid >> 2, q = tid & 3;
    const int prl = patch >> 4, pc = patch & 15;
    const int row = 1 + prl*8 + q*2;
    float s = 0.f;
#pragma unroll
    for (int r2 = 0; r2 < 2; ++r2)
#pragma unroll
      for (int j = 0; j < 4; ++j) {
        const float4 vv = *reinterpret_cast<const float4*>(&xt[(row + r2)*256 + pc*16 + j*4]);
        s += fabsf(vv.x) + fabsf(vv.y) + fabsf(vv.z) + fabsf(vv.w);
      }
    s += __shfl_down(s, 1);
    s += __shfl_down(s, 2);
    if (q == 0) scores[tb*NP_ + chunk*64 + patch] = s * (1.f/128.f);
  }
  // ---- padded downsample ----
  float* Pt = P + (size_t)tb * PTB;
  if (tid < 128) {                     // zero col pads (px -2,-1,64,65) for our 16 rows
    const int r = tid >> 3, rem = tid & 7;
    const int px4 = rem >> 1, ci = rem & 1;
    const int px = (px4 < 2) ? (px4 - 2) : (62 + px4);
    Pt[(r0 + r + 1)*PROW + (px + 2)*2 + ci] = 0.f;
  }
  if (chunk == 0 && tid < PROW) Pt[tid] = 0.f;            // pad row -1
  if (chunk == 3 && tid < PROW) Pt[65*PROW + tid] = 0.f;  // pad row 64
#pragma unroll
  for (int k = 0; k < 8; ++k) {
    const int idx = k*256 + tid;       // (row16*64+col)*2+ci
    const int ci = idx & 1, rest = idx >> 1;
    const int col = rest & 63, row16 = rest >> 6;
    const int pr = r0 + row16;
    float wy0=0.125f, wy1=0.375f, wy2=0.375f, wy3=0.125f;
    if (pr == 0)       { wy0=0.f;     wy1=3.f/7.f; wy2=3.f/7.f; wy3=1.f/7.f; }
    else if (pr == 63) { wy0=1.f/7.f; wy1=3.f/7.f; wy2=3.f/7.f; wy3=0.f; }
    float wx0=0.125f, wx1=0.375f, wx2=0.375f, wx3=0.125f;
    if (col == 0)       { wx0=0.f;     wx1=3.f/7.f; wx2=3.f/7.f; wx3=1.f/7.f; }
    else if (col == 63) { wx0=1.f/7.f; wx1=3.f/7.f; wx2=3.f/7.f; wx3=0.f; }
    const int lr = 2*row16;            // xt row of tap j=0
    const int cc0 = 2*col - 1;
    float val = 0.f;
#pragma unroll
    for (int j = 0; j < 4; ++j) {
      const float wyj = (j==0)?wy0:(j==1)?wy1:(j==2)?wy2:wy3;
      float h = 0.f;
#pragma unroll
      for (int i = 0; i < 4; ++i) {
        const float wxi = (i==0)?wx0:(i==1)?wx1:(i==2)?wx2:wx3;
        int cc = cc0 + i; cc = cc < 0 ? 0 : (cc > W_-1 ? W_-1 : cc);
        h += wxi * xt[(lr + j)*256 + cc*2 + ci];
      }
      val += wyj * h;
    }
    Pt[(pr + 1)*PROW + (col + 2)*2 + ci] = val;
  }
}

// ---------------- K2: rank+argmax, window dump, fovea conv -> saliency -> channel gate ----------------
__global__ void __launch_bounds__(512) k_gate(const float* __restrict__ x,
    const float* __restrict__ scores, const float* __restrict__ wf,
    float* __restrict__ Wfbuf, float* __restrict__ chan_gate,
    unsigned* __restrict__ route_count, unsigned* __restrict__ chan_count) {
  const int tb = blockIdx.x, tid = threadIdx.x;
  __shared__ float sm[NP_];
  __shared__ __align__(16) float tile[34*68];   // [34 rows][34 px * 2ch], zero-padded
  __shared__ float salred[512];
  __shared__ float salv[64];
  __shared__ int2 syx;
  if (tid < 256) sm[tid] = scores[tb*NP_ + tid];
  __syncthreads();
  if (tid < 256) {
    const float v = sm[tid];
    int cg = 0, eqb = 0;
    for (int q = 0; q < NP_; ++q) {
      cg  += (sm[q] > v) ? 1 : 0;
      eqb += ((sm[q] == v) && (q < tid)) ? 1 : 0;
    }
    if (cg < 4) atomicAdd(&route_count[tid], 1u);
    if (cg == 0 && eqb == 0) {
      const int cy = (tid >> 4)*8 + 4, cx = (tid & 15)*8 + 4;
      int y0 = cy - 16; y0 = y0 < 0 ? 0 : (y0 > 96 ? 96 : y0);
      int x0 = cx - 16; x0 = x0 < 0 ? 0 : (x0 > 96 ? 96 : x0);
      syx = make_int2(y0, x0);
    }
  }
  for (int i = tid; i < 34*68; i += 512) tile[i] = 0.f;
  __syncthreads();
  const int2 yx = syx;
  {                                    // fill interior: 32 rows x 16 segs x 2px
    const int row = tid >> 4, seg = tid & 15;
    const float* src = x + (size_t)tb*32768 + (size_t)(yx.x + row)*256 + (yx.y + seg*2)*2;
    float2 a = *reinterpret_cast<const float2*>(src);
    float2 bq = *reinterpret_cast<const float2*>(src + 2);
    a.x  = (fabsf(a.x)  > 0.5f) ? a.x  : 0.f;
    a.y  = (fabsf(a.y)  > 0.5f) ? a.y  : 0.f;
    bq.x = (fabsf(bq.x) > 0.5f) ? bq.x : 0.f;
    bq.y = (fabsf(bq.y) > 0.5f) ? bq.y : 0.f;
    float* dst = &tile[(row + 1)*68 + (seg*2 + 1)*2];
    *reinterpret_cast<float2*>(dst)     = a;
    *reinterpret_cast<float2*>(dst + 2) = bq;
  }
  __syncthreads();
  {                                    // dump padded masked window for k_mem
    float* dst = Wfbuf + (size_t)tb*WTB;
    for (int i = tid; i < WTB/4; i += 512)
      *reinterpret_cast<float4*>(dst + i*4) = *reinterpret_cast<const float4*>(&tile[i*4]);
  }
  const int c = tid & 63, grp = tid >> 6, xg = grp & 3, rh = grp >> 2;
  float wreg[18];
#pragma unroll
  for (int k = 0; k < 18; ++k) wreg[k] = wf[k*CF_ + c];
  const float* tbase = &tile[(rh*16)*68 + xg*16];
  float4 wb[3][5];
#pragma unroll
  for (int m = 0; m < 5; ++m) {
    wb[0][m] = *reinterpret_cast<const float4*>(tbase + m*4);
    wb[1][m] = *reinterpret_cast<const float4*>(tbase + 68 + m*4);
  }
  float sal = 0.f;
#pragma unroll
  for (int yy = 0; yy < 16; ++yy) {
#pragma unroll
    for (int m = 0; m < 5; ++m)
      wb[(yy+2)%3][m] = *reinterpret_cast<const float4*>(tbase + (yy+2)*68 + m*4);
#pragma unroll
    for (int k = 0; k < 8; ++k) {
      float acc = 0.f;
#pragma unroll
      for (int dy = 0; dy < 3; ++dy) {
#pragma unroll
        for (int dx = 0; dx < 3; ++dx) {
          const int r = k + dx;
          const float4 f = wb[(yy+dy)%3][r >> 1];
          acc += f4c(f, (r&1)*2)     * wreg[(dy*3+dx)*2]
               + f4c(f, (r&1)*2 + 1) * wreg[(dy*3+dx)*2 + 1];
        }
      }
      sal += fabsf(acc);
    }
  }
  salred[grp*64 + c] = sal;
  __syncthreads();
  if (tid < 64) {
    float s = 0.f;
#pragma unroll
    for (int g = 0; g < 8; ++g) s += salred[g*64 + tid];
    salv[tid] = s * (1.f/1024.f);
  }
  __syncthreads();
  if (tid < 64) {
    const float sv = salv[tid];
    int cg = 0;
    for (int q = 0; q < 64; ++q) cg += (salv[q] > sv) ? 1 : 0;
    const float gate = (cg < 16) ? 1.f : 0.f;
    chan_gate[tb*CF_ + tid] = gate;
    if (gate > 0.f) atomicAdd(&chan_count[tid], 1u);
  }
}

// ---------------- K3: persistent membranes, 2px/lane, packed-fp32 channel pairs, ballot counting ----------------
// fovea:  blocks 0..2047  = b*64 + cp*2 + half ; wave w: rows half*16+w*4 .. +3
//         lane l: row += l>>4, px0 = (l&15)*2
// periph: blocks 2048..6143 = 2048 + b*128 + cp*8 + rq ; wave w: rows rq*8+w*2 .. +1
//         lane l: row += l>>5, px0 = (l&31)*2
// fov_part: u32 [t][b][cp32][8]  (cnt0 | cnt1<<16)
// per_part: u32 [t][b][cp16][32]
__global__ void __launch_bounds__(256, 4) k_mem(const float* __restrict__ Wfbuf,
    const float* __restrict__ P, const float* __restrict__ wf, const float* __restrict__ wp,
    const float* __restrict__ chan_gate,
    unsigned* __restrict__ fov_part, unsigned* __restrict__ per_part) {
  const int tid = threadIdx.x;
  const int w = tid >> 6, l = tid & 63;
  if (blockIdx.x < 2048) {
    const int blk = blockIdx.x;
    const int b = blk >> 6, rem = blk & 63, cp = rem >> 1, half = rem & 1;
    const int ch0 = cp*2;
    const int row = half*16 + w*4 + (l >> 4);
    const int px0 = (l & 15)*2;
    f2 w01[18];                        // {ch0,ch1} weight pairs
#pragma unroll
    for (int k = 0; k < 18; ++k) {
      f2 t; t.x = wf[k*CF_ + ch0]; t.y = wf[k*CF_ + ch0 + 1];
      w01[k] = t;
    }
    f2 va = (f2)0.f, vb = (f2)0.f;     // membranes: px a/b, channel pair
    for (int t = 0; t < T_; ++t) {
      const int tb = t*B_ + b;
      const float* base = Wfbuf + (size_t)tb*WTB + (size_t)row*68 + px0*2;
      f2 aa = (f2)0.f, ab = (f2)0.f;
#pragma unroll
      for (int dy = 0; dy < 3; ++dy) {
        const float4 fa = *reinterpret_cast<const float4*>(base + dy*68);
        const float4 fb = *reinterpret_cast<const float4*>(base + dy*68 + 4);
        const float cx[4] = {fa.x, fa.z, fb.x, fb.z};
        const float cy[4] = {fa.y, fa.w, fb.y, fb.w};
#pragma unroll
        for (int dx = 0; dx < 3; ++dx) {
          const f2 wx = w01[dy*6 + dx*2], wy = w01[dy*6 + dx*2 + 1];
          aa += cx[dx]*wx   + cy[dx]*wy;
          ab += cx[dx+1]*wx + cy[dx+1]*wy;
        }
      }
      f2 g; g.x = chan_gate[tb*CF_ + ch0]; g.y = chan_gate[tb*CF_ + ch0 + 1];
      f2 na = 0.9f*va + aa*g;
      f2 nb = 0.9f*vb + ab*g;
      const bool s0a = na.x > 1.f, s1a = na.y > 1.f, s0b = nb.x > 1.f, s1b = nb.y > 1.f;
      va.x = s0a ? na.x - 1.f : na.x;
      va.y = s1a ? na.y - 1.f : na.y;
      vb.x = s0b ? nb.x - 1.f : nb.x;
      vb.y = s1b ? nb.y - 1.f : nb.y;
      const unsigned long long m0a = __ballot(s0a), m0b = __ballot(s0b);
      const unsigned long long m1a = __ballot(s1a), m1b = __ballot(s1b);
      const unsigned packed = (unsigned)(__popcll(m0a) + __popcll(m0b))
                            | ((unsigned)(__popcll(m1a) + __popcll(m1b)) << 16);
      if (l == 0) fov_part[((size_t)tb*32 + cp)*8 + half*4 + w] = packed;
    }
  } else {
    const int blk = blockIdx.x - 2048;
    const int b = blk >> 7, rem = blk & 127, cp = rem >> 3, rq = rem & 7;
    const int ch0 = cp*2;
    const int row = rq*8 + w*2 + (l >> 5);
    const int px0 = (l & 31)*2;
    f2 w01[18];
#pragma unroll
    for (int k = 0; k < 18; ++k) {
      f2 t; t.x = wp[k*CP_ + ch0]; t.y = wp[k*CP_ + ch0 + 1];
      w01[k] = t;
    }
    f2 va = (f2)0.f, vb = (f2)0.f;
    for (int t = 0; t < T_; ++t) {
      const int tb = t*B_ + b;
      const float* base = P + (size_t)tb*PTB + (size_t)row*PROW + px0*2;
      f2 aa = (f2)0.f, ab = (f2)0.f;
#pragma unroll
      for (int dy = 0; dy < 3; ++dy) {
        const float4 f0 = *reinterpret_cast<const float4*>(base + dy*PROW);
        const float4 f1 = *reinterpret_cast<const float4*>(base + dy*PROW + 4);
        const float4 f2v = *reinterpret_cast<const float4*>(base + dy*PROW + 8);
        const float cx[6] = {f0.x, f0.z, f1.x, f1.z, f2v.x, f2v.z};
        const float cy[6] = {f0.y, f0.w, f1.y, f1.w, f2v.y, f2v.w};
#pragma unroll
        for (int dx = 0; dx < 3; ++dx) {
          const f2 wx = w01[dy*6 + dx*2], wy = w01[dy*6 + dx*2 + 1];
          aa += cx[dx+1]*wx + cy[dx+1]*wy;
          ab += cx[dx+2]*wx + cy[dx+2]*wy;
        }
      }
      f2 na = 0.9f*va + aa;
      f2 nb = 0.9f*vb + ab;
      const bool s0a = na.x > 1.f, s1a = na.y > 1.f, s0b = nb.x > 1.f, s1b = nb.y > 1.f;
      va.x = s0a ? na.x - 1.f : na.x;
      va.y = s1a ? na.y - 1.f : na.y;
      vb.x = s0b ? nb.x - 1.f : nb.x;
      vb.y = s1b ? nb.y - 1.f : nb.y;
      const unsigned long long m0a = __ballot(s0a), m0b = __ballot(s0b);
      const unsigned long long m1a = __ballot(s1a), m1b = __ballot(s1b);
      const unsigned packed = (unsigned)(__popcll(m0a) + __popcll(m0b))
                            | ((unsigned)(__popcll(m1a) + __popcll(m1b)) << 16);
      if (l == 0) per_part[((size_t)tb*16 + cp)*32 + rq*4 + w] = packed;
    }
  }
}

// ---------------- K4: reduce partials + logits ----------------
__global__ void __launch_bounds__(256) k_logits(const float* __restrict__ scores,
    const unsigned* __restrict__ fov_part, const unsigned* __restrict__ per_part,
    const float* __restrict__ head_w, const float* __restrict__ head_b,
    const float* __restrict__ route_w, const float* __restrict__ route_b,
    float* __restrict__ logits, unsigned* __restrict__ tot) {
  const int tb = blockIdx.x, tid = threadIdx.x;
  __shared__ float sc[NP_];
  __shared__ float fu[96];
  sc[tid] = scores[tb*NP_ + tid];
  if (tid < 64) {
    const unsigned* fp = fov_part + (size_t)tb*256;   // 32 cp * 8
    const int cp = tid >> 1, sh = (tid & 1)*16;
    unsigned fsum = 0;
#pragma unroll
    for (int i = 0; i < 8; ++i) fsum += (fp[cp*8 + i] >> sh) & 0xFFFFu;
    fu[tid] = (float)fsum * (1.f/1024.f);
    unsigned r = fsum;
#pragma unroll
    for (int off = 32; off > 0; off >>= 1) r += __shfl_down(r, off);
    if (tid == 0) atomicAdd(&tot[0], r);
  } else if (tid < 128) {
    const int c = tid - 64;            // 0..63, only c<32 active
    unsigned psum = 0;
    if (c < 32) {
      const unsigned* pp = per_part + (size_t)tb*512;  // 16 cp * 32
      const int cp = c >> 1, sh = (c & 1)*16;
#pragma unroll 8
      for (int i = 0; i < 32; ++i) psum += (pp[cp*32 + i] >> sh) & 0xFFFFu;
      fu[64 + c] = (float)psum * (1.f/4096.f);
    }
    unsigned r = psum;
#pragma unroll
    for (int off = 32; off > 0; off >>= 1) r += __shfl_down(r, off);
    if (tid == 64) atomicAdd(&tot[1], r);
  }
  __syncthreads();
  if (tid < 128) {
    const int o = tid;
    float acc = head_b[o] + route_b[o];
#pragma unroll 8
    for (int k = 0; k < 96; ++k)  acc += fu[k]*head_w[k*OUT_ + o];
#pragma unroll 8
    for (int p = 0; p < NP_; ++p) acc += sc[p]*route_w[p*OUT_ + o];
    logits[tb*OUT_ + o] = acc;
  }
}

// ---------------- K5: finalize ----------------
__global__ void __launch_bounds__(256) k_final(const float* __restrict__ logits,
    float* __restrict__ dout, const unsigned* __restrict__ cnts) {
  const int blk = blockIdx.x, tid = threadIdx.x;
  if (blk < 16) {
    const int idx = blk*256 + tid;
    const int b = idx >> 7, o = idx & 127;
    float s = 0.f;
#pragma unroll
    for (int t = 0; t < T_; ++t) s += logits[(t*B_ + b)*OUT_ + o];
    dout[idx] = s * (1.f/32.f);
  } else {
    if (tid == 0) {
      dout[OFF_SR]     = (float)cnts[321] * (1.f/67108864.f);   // T*B*32*32*64
      dout[OFF_SR + 1] = (float)cnts[322] * (1.f/134217728.f);  // T*B*64*64*32
      dout[OFF_ACTIVE] = (float)cnts[0]   * (1.f/33554432.f);   // T*B*H*W*C
    }
    dout[OFF_ROUTE + tid] = (float)cnts[1 + tid] * (1.f/1024.f);
    if (tid < 64) dout[OFF_CHAN + tid] = (float)cnts[257 + tid] * (1.f/1024.f);
  }
}

extern "C" void kernel_launch(void* const* d_in, const int* in_sizes, int n_in,
                              void* d_out, int out_size, void* d_ws, size_t ws_size,
                              hipStream_t stream) {
  const float* x       = (const float*)d_in[0];
  const float* wf      = (const float*)d_in[1];
  const float* wp      = (const float*)d_in[2];
  const float* head_w  = (const float*)d_in[3];
  const float* head_b  = (const float*)d_in[4];
  const float* route_w = (const float*)d_in[5];
  const float* route_b = (const float*)d_in[6];
  float* out = (float*)d_out;

  float*    ws_P      = (float*)d_ws;                         // 1024*8976 floats (36.8 MB)
  float*    ws_Wf     = ws_P + (size_t)1024*PTB;              // 1024*2312 floats (9.5 MB)
  float*    ws_scores = ws_Wf + (size_t)1024*WTB;             // 262144 floats
  float*    ws_gate   = ws_scores + T_*B_*NP_;                // 65536 floats
  unsigned* fov_part  = (unsigned*)(ws_gate + T_*B_*CF_);     // 32*32*32*8 u32 (1 MB)
  unsigned* per_part  = fov_part + (size_t)T_*B_*256;         // 32*32*16*32 u32 (2 MB)
  unsigned* ws_cnt    = per_part + (size_t)T_*B_*512;

  hipMemsetAsync(ws_cnt, 0, CNT_N*sizeof(unsigned), stream);

  k_pre   <<<T_*B_*4, 256, 0, stream>>>(x, ws_scores, ws_P, ws_cnt);
  k_gate  <<<T_*B_,   512, 0, stream>>>(x, ws_scores, wf, ws_Wf, ws_gate,
                                        ws_cnt + 1, ws_cnt + 257);
  k_mem   <<<6144,    256, 0, stream>>>(ws_Wf, ws_P, wf, wp, ws_gate,
                                        fov_part, per_part);
  k_logits<<<T_*B_,   256, 0, stream>>>(ws_scores, fov_part, per_part, head_w, head_b,
                                        route_w, route_b, out + OFF_LOGITS, ws_cnt + 321);
  k_final <<<17, 256, 0, stream>>>(out + OFF_LOGITS, out, ws_cnt);
}

// Round 9
// 272.546 us; speedup vs baseline: 6.0915x; 1.1367x over previous
//
#include <hip/hip_runtime.h>

#define T_ 32
#define B_ 32
#define H_ 128
#define W_ 128
#define C_ 2
#define NP_ 256
#define CF_ 64
#define CP_ 32
#define OUT_ 128

// padded periph image: rows -1..64 (66), px -2..65 (68) * 2ch = 136 floats/row
#define PROW 136
#define PTB  8976    // 66*136 floats per (t,b)
// padded fovea window: 34 rows x 34 px x 2ch = 2312 floats per (t,b)
#define WTB  2312

// d_out layout (floats): out(4096) | logits_seq(131072) | sr(2) | active(1) | route(256) | chan(64)
#define OFF_LOGITS 4096
#define OFF_SR     135168
#define OFF_ACTIVE 135170
#define OFF_ROUTE  135171
#define OFF_CHAN   135427

// ws_cnt layout (u32): [0]=active  [1..256]=route  [257..320]=chan  [321]=totf  [322]=totp
#define CNT_N 323

typedef float f2 __attribute__((ext_vector_type(2)));

__device__ __forceinline__ float f4c(const float4& v, int i) {
  switch (i & 3) { case 0: return v.x; case 1: return v.y; case 2: return v.z; default: return v.w; }
}

// ---------------- K1: per-(t,b) everything pre-membrane ----------------
// stage+mask+event count+patch scores+downsample (4 chunks), rank/argmax,
// fovea window dump, fovea conv->saliency->channel gate.
__global__ void __launch_bounds__(256) k_pre(const float* __restrict__ x,
    const float* __restrict__ wf,
    float* __restrict__ scores_g, float* __restrict__ P, float* __restrict__ Wfbuf,
    float* __restrict__ chan_gate, unsigned* __restrict__ cnts) {
  const int tb = blockIdx.x, tid = threadIdx.x;
  __shared__ __align__(16) float xt[34*256];   // staging / later fovea tile
  __shared__ float sm[NP_];
  __shared__ float salred[256];
  __shared__ float salv[64];
  __shared__ unsigned wsum[4];
  __shared__ int2 syx;
  const float* img = x + (size_t)tb*32768;
  unsigned cnt = 0;
  for (int chunk = 0; chunk < 4; ++chunk) {
    const int r0 = chunk*16;
    __syncthreads();                    // xt safe to overwrite
    for (int i4 = tid; i4 < 34*64; i4 += 256) {
      const int rr = i4 >> 6, off4 = i4 & 63;
      const int xr = 2*r0 - 1 + rr;
      float4 vv = make_float4(0.f, 0.f, 0.f, 0.f);
      if (xr >= 0 && xr < H_) {
        vv = *reinterpret_cast<const float4*>(img + (size_t)xr*256 + off4*4);
        if (rr >= 1 && rr <= 32) {
          cnt += (fabsf(vv.x) > 0.5f) + (fabsf(vv.y) > 0.5f)
               + (fabsf(vv.z) > 0.5f) + (fabsf(vv.w) > 0.5f);
        }
        vv.x = (fabsf(vv.x) > 0.5f) ? vv.x : 0.f;
        vv.y = (fabsf(vv.y) > 0.5f) ? vv.y : 0.f;
        vv.z = (fabsf(vv.z) > 0.5f) ? vv.z : 0.f;
        vv.w = (fabsf(vv.w) > 0.5f) ? vv.w : 0.f;
      }
      *reinterpret_cast<float4*>(&xt[i4*4]) = vv;
    }
    __syncthreads();
    // ---- patch scores: 64 patches, 4 threads/patch ----
    {
      const int patch = tid >> 2, q = tid & 3;
      const int prl = patch >> 4, pc = patch & 15;
      const int row = 1 + prl*8 + q*2;
      float s = 0.f;
#pragma unroll
      for (int r2 = 0; r2 < 2; ++r2)
#pragma unroll
        for (int j = 0; j < 4; ++j) {
          const float4 vv = *reinterpret_cast<const float4*>(&xt[(row + r2)*256 + pc*16 + j*4]);
          s += fabsf(vv.x) + fabsf(vv.y) + fabsf(vv.z) + fabsf(vv.w);
        }
      s += __shfl_down(s, 1);
      s += __shfl_down(s, 2);
      if (q == 0) {
        const float sv = s * (1.f/128.f);
        sm[chunk*64 + patch] = sv;
        scores_g[tb*NP_ + chunk*64 + patch] = sv;
      }
    }
    // ---- padded downsample ----
    float* Pt = P + (size_t)tb * PTB;
    if (tid < 128) {                   // zero col pads for our 16 rows
      const int r = tid >> 3, rem = tid & 7;
      const int px4 = rem >> 1, ci = rem & 1;
      const int px = (px4 < 2) ? (px4 - 2) : (62 + px4);
      Pt[(r0 + r + 1)*PROW + (px + 2)*2 + ci] = 0.f;
    }
    if (chunk == 0 && tid < PROW) Pt[tid] = 0.f;            // pad row -1
    if (chunk == 3 && tid < PROW) Pt[65*PROW + tid] = 0.f;  // pad row 64
#pragma unroll
    for (int k = 0; k < 8; ++k) {
      const int idx = k*256 + tid;
      const int ci = idx & 1, rest = idx >> 1;
      const int col = rest & 63, row16 = rest >> 6;
      const int pr = r0 + row16;
      float wy0=0.125f, wy1=0.375f, wy2=0.375f, wy3=0.125f;
      if (pr == 0)       { wy0=0.f;     wy1=3.f/7.f; wy2=3.f/7.f; wy3=1.f/7.f; }
      else if (pr == 63) { wy0=1.f/7.f; wy1=3.f/7.f; wy2=3.f/7.f; wy3=0.f; }
      float wx0=0.125f, wx1=0.375f, wx2=0.375f, wx3=0.125f;
      if (col == 0)       { wx0=0.f;     wx1=3.f/7.f; wx2=3.f/7.f; wx3=1.f/7.f; }
      else if (col == 63) { wx0=1.f/7.f; wx1=3.f/7.f; wx2=3.f/7.f; wx3=0.f; }
      const int lr = 2*row16;
      const int cc0 = 2*col - 1;
      float val = 0.f;
#pragma unroll
      for (int j = 0; j < 4; ++j) {
        const float wyj = (j==0)?wy0:(j==1)?wy1:(j==2)?wy2:wy3;
        float h = 0.f;
#pragma unroll
        for (int i = 0; i < 4; ++i) {
          const float wxi = (i==0)?wx0:(i==1)?wx1:(i==2)?wx2:wx3;
          int cc = cc0 + i; cc = cc < 0 ? 0 : (cc > W_-1 ? W_-1 : cc);
          h += wxi * xt[(lr + j)*256 + cc*2 + ci];
        }
        val += wyj * h;
      }
      Pt[(pr + 1)*PROW + (col + 2)*2 + ci] = val;
    }
  }
  // ---- event-count reduce ----
  unsigned c64 = cnt;
#pragma unroll
  for (int off = 32; off > 0; off >>= 1) c64 += __shfl_down(c64, off);
  if ((tid & 63) == 0) wsum[tid >> 6] = c64;
  __syncthreads();                      // sm complete, wsum visible, xt readers done
  if (tid == 0) atomicAdd(&cnts[0], wsum[0] + wsum[1] + wsum[2] + wsum[3]);
  // ---- rank + first-index argmax ----
  {
    const float v = sm[tid];
    int cg = 0, eqb = 0;
    for (int q = 0; q < NP_; ++q) {
      cg  += (sm[q] > v) ? 1 : 0;
      eqb += ((sm[q] == v) && (q < tid)) ? 1 : 0;
    }
    if (cg < 4) atomicAdd(&cnts[1 + tid], 1u);
    if (cg == 0 && eqb == 0) {
      const int cy = (tid >> 4)*8 + 4, cx = (tid & 15)*8 + 4;
      int y0 = cy - 16; y0 = y0 < 0 ? 0 : (y0 > 96 ? 96 : y0);
      int x0 = cx - 16; x0 = x0 < 0 ? 0 : (x0 > 96 ? 96 : x0);
      syx = make_int2(y0, x0);
    }
  }
  // ---- zero fovea tile (reuse xt as tile[34*68]) ----
  float* tile = xt;
  for (int i = tid; i < 34*68; i += 256) tile[i] = 0.f;
  __syncthreads();                      // syx visible, zeros done
  const int2 yx = syx;
  {                                     // fill interior: 32 rows x 8 segs x 4px
    const int row = tid >> 3, seg = tid & 7;
    const float* src = img + (size_t)(yx.x + row)*256 + (yx.y + seg*4)*2;
    float4 a = *reinterpret_cast<const float4*>(src);
    float4 b4 = *reinterpret_cast<const float4*>(src + 4);
    a.x  = (fabsf(a.x)  > 0.5f) ? a.x  : 0.f;
    a.y  = (fabsf(a.y)  > 0.5f) ? a.y  : 0.f;
    a.z  = (fabsf(a.z)  > 0.5f) ? a.z  : 0.f;
    a.w  = (fabsf(a.w)  > 0.5f) ? a.w  : 0.f;
    b4.x = (fabsf(b4.x) > 0.5f) ? b4.x : 0.f;
    b4.y = (fabsf(b4.y) > 0.5f) ? b4.y : 0.f;
    b4.z = (fabsf(b4.z) > 0.5f) ? b4.z : 0.f;
    b4.w = (fabsf(b4.w) > 0.5f) ? b4.w : 0.f;
    float* dst = &tile[(row + 1)*68 + (seg*4 + 1)*2];
    *reinterpret_cast<float2*>(dst)     = make_float2(a.x, a.y);
    *reinterpret_cast<float2*>(dst + 2) = make_float2(a.z, a.w);
    *reinterpret_cast<float2*>(dst + 4) = make_float2(b4.x, b4.y);
    *reinterpret_cast<float2*>(dst + 6) = make_float2(b4.z, b4.w);
  }
  __syncthreads();
  {                                     // dump padded masked window for k_mem
    float* dst = Wfbuf + (size_t)tb*WTB;
    for (int i = tid; i < WTB/4; i += 256)
      *reinterpret_cast<float4*>(dst + i*4) = *reinterpret_cast<const float4*>(&tile[i*4]);
  }
  // ---- fovea conv -> saliency (4 x-groups of 8px, all 32 rows/thread) ----
  const int c = tid & 63, xg = tid >> 6;
  float wreg[18];
#pragma unroll
  for (int k = 0; k < 18; ++k) wreg[k] = wf[k*CF_ + c];
  const float* tbase = &tile[xg*16];
  float4 wb[3][5];
#pragma unroll
  for (int m = 0; m < 5; ++m) {
    wb[0][m] = *reinterpret_cast<const float4*>(tbase + m*4);
    wb[1][m] = *reinterpret_cast<const float4*>(tbase + 68 + m*4);
  }
  float sal = 0.f;
#pragma unroll
  for (int yy = 0; yy < 32; ++yy) {
#pragma unroll
    for (int m = 0; m < 5; ++m)
      wb[(yy+2)%3][m] = *reinterpret_cast<const float4*>(tbase + (yy+2)*68 + m*4);
#pragma unroll
    for (int k = 0; k < 8; ++k) {
      float acc = 0.f;
#pragma unroll
      for (int dy = 0; dy < 3; ++dy) {
#pragma unroll
        for (int dx = 0; dx < 3; ++dx) {
          const int r = k + dx;
          const float4 f = wb[(yy+dy)%3][r >> 1];
          acc += f4c(f, (r&1)*2)     * wreg[(dy*3+dx)*2]
               + f4c(f, (r&1)*2 + 1) * wreg[(dy*3+dx)*2 + 1];
        }
      }
      sal += fabsf(acc);
    }
  }
  salred[tid] = sal;
  __syncthreads();
  if (tid < 64)
    salv[tid] = (salred[tid] + salred[64+tid] + salred[128+tid] + salred[192+tid]) * (1.f/1024.f);
  __syncthreads();
  if (tid < 64) {
    const float sv = salv[tid];
    int cg = 0;
    for (int q = 0; q < 64; ++q) cg += (salv[q] > sv) ? 1 : 0;
    const float gate = (cg < 16) ? 1.f : 0.f;
    chan_gate[tb*CF_ + tid] = gate;
    if (gate > 0.f) atomicAdd(&cnts[257 + tid], 1u);
  }
}

// ---------------- K2: persistent membranes, 2px/lane, pk-f32, ballot, 2-deep SW pipeline ----------------
__global__ void __launch_bounds__(256, 4) k_mem(const float* __restrict__ Wfbuf,
    const float* __restrict__ P, const float* __restrict__ wf, const float* __restrict__ wp,
    const float* __restrict__ chan_gate,
    unsigned* __restrict__ fov_part, unsigned* __restrict__ per_part) {
  const int tid = threadIdx.x;
  const int w = tid >> 6, l = tid & 63;
  if (blockIdx.x < 2048) {
    const int blk = blockIdx.x;
    const int b = blk >> 6, rem = blk & 63, cp = rem >> 1, half = rem & 1;
    const int ch0 = cp*2;
    const int row = half*16 + w*4 + (l >> 4);
    const int px0 = (l & 15)*2;
    f2 w01[18];
#pragma unroll
    for (int k = 0; k < 18; ++k) {
      f2 t_; t_.x = wf[k*CF_ + ch0]; t_.y = wf[k*CF_ + ch0 + 1];
      w01[k] = t_;
    }
    const float* p0 = Wfbuf + (size_t)b*WTB + (size_t)row*68 + px0*2;
    const float* gp = chan_gate + b*CF_ + ch0;
    const unsigned obase = (unsigned)((b*32 + cp)*8 + half*4 + w);
    f2 va = (f2)0.f, vb = (f2)0.f;
    float4 A[6], Bv[6];
    f2 gA, gB;
#pragma unroll
    for (int dy = 0; dy < 3; ++dy) {
      A[2*dy]   = *reinterpret_cast<const float4*>(p0 + dy*68);
      A[2*dy+1] = *reinterpret_cast<const float4*>(p0 + dy*68 + 4);
    }
    gA.x = gp[0]; gA.y = gp[1];
    for (int t = 0; t < T_; t += 2) {
      {
        const float* p1 = p0 + (size_t)(t + 1)*(B_*WTB);
#pragma unroll
        for (int dy = 0; dy < 3; ++dy) {
          Bv[2*dy]   = *reinterpret_cast<const float4*>(p1 + dy*68);
          Bv[2*dy+1] = *reinterpret_cast<const float4*>(p1 + dy*68 + 4);
        }
        gB.x = gp[(t + 1)*B_*CF_]; gB.y = gp[(t + 1)*B_*CF_ + 1];
      }
      {                                 // compute t from A
        f2 aa = (f2)0.f, ab = (f2)0.f;
#pragma unroll
        for (int dy = 0; dy < 3; ++dy) {
          const float4 fa = A[2*dy], fb = A[2*dy+1];
          const f2 w0 = w01[dy*6], w0y = w01[dy*6+1], w1 = w01[dy*6+2],
                   w1y = w01[dy*6+3], w2 = w01[dy*6+4], w2y = w01[dy*6+5];
          aa += fa.x*w0 + fa.y*w0y + fa.z*w1 + fa.w*w1y + fb.x*w2 + fb.y*w2y;
          ab += fa.z*w0 + fa.w*w0y + fb.x*w1 + fb.y*w1y + fb.z*w2 + fb.w*w2y;
        }
        f2 na = 0.9f*va + aa*gA;
        f2 nb = 0.9f*vb + ab*gA;
        const bool s0a = na.x > 1.f, s1a = na.y > 1.f, s0b = nb.x > 1.f, s1b = nb.y > 1.f;
        va.x = s0a ? na.x - 1.f : na.x;  va.y = s1a ? na.y - 1.f : na.y;
        vb.x = s0b ? nb.x - 1.f : nb.x;  vb.y = s1b ? nb.y - 1.f : nb.y;
        const unsigned packed =
            (unsigned)(__popcll(__ballot(s0a)) + __popcll(__ballot(s0b)))
          | ((unsigned)(__popcll(__ballot(s1a)) + __popcll(__ballot(s1b))) << 16);
        if (l == 0) fov_part[obase + (unsigned)t*8192u] = packed;
      }
      if (t + 2 < T_) {
        const float* p2 = p0 + (size_t)(t + 2)*(B_*WTB);
#pragma unroll
        for (int dy = 0; dy < 3; ++dy) {
          A[2*dy]   = *reinterpret_cast<const float4*>(p2 + dy*68);
          A[2*dy+1] = *reinterpret_cast<const float4*>(p2 + dy*68 + 4);
        }
        gA.x = gp[(t + 2)*B_*CF_]; gA.y = gp[(t + 2)*B_*CF_ + 1];
      }
      {                                 // compute t+1 from Bv
        f2 aa = (f2)0.f, ab = (f2)0.f;
#pragma unroll
        for (int dy = 0; dy < 3; ++dy) {
          const float4 fa = Bv[2*dy], fb = Bv[2*dy+1];
          const f2 w0 = w01[dy*6], w0y = w01[dy*6+1], w1 = w01[dy*6+2],
                   w1y = w01[dy*6+3], w2 = w01[dy*6+4], w2y = w01[dy*6+5];
          aa += fa.x*w0 + fa.y*w0y + fa.z*w1 + fa.w*w1y + fb.x*w2 + fb.y*w2y;
          ab += fa.z*w0 + fa.w*w0y + fb.x*w1 + fb.y*w1y + fb.z*w2 + fb.w*w2y;
        }
        f2 na = 0.9f*va + aa*gB;
        f2 nb = 0.9f*vb + ab*gB;
        const bool s0a = na.x > 1.f, s1a = na.y > 1.f, s0b = nb.x > 1.f, s1b = nb.y > 1.f;
        va.x = s0a ? na.x - 1.f : na.x;  va.y = s1a ? na.y - 1.f : na.y;
        vb.x = s0b ? nb.x - 1.f : nb.x;  vb.y = s1b ? nb.y - 1.f : nb.y;
        const unsigned packed =
            (unsigned)(__popcll(__ballot(s0a)) + __popcll(__ballot(s0b)))
          | ((unsigned)(__popcll(__ballot(s1a)) + __popcll(__ballot(s1b))) << 16);
        if (l == 0) fov_part[obase + (unsigned)(t + 1)*8192u] = packed;
      }
    }
  } else {
    const int blk = blockIdx.x - 2048;
    const int b = blk >> 7, rem = blk & 127, cp = rem >> 3, rq = rem & 7;
    const int ch0 = cp*2;
    const int row = rq*8 + w*2 + (l >> 5);
    const int px0 = (l & 31)*2;
    f2 w01[18];
#pragma unroll
    for (int k = 0; k < 18; ++k) {
      f2 t_; t_.x = wp[k*CP_ + ch0]; t_.y = wp[k*CP_ + ch0 + 1];
      w01[k] = t_;
    }
    const float* p0 = P + (size_t)b*PTB + (size_t)row*PROW + px0*2;
    const unsigned obase = (unsigned)((b*16 + cp)*32 + rq*4 + w);
    f2 va = (f2)0.f, vb = (f2)0.f;
    float4 A[9], Bv[9];
#pragma unroll
    for (int dy = 0; dy < 3; ++dy) {
      A[3*dy]   = *reinterpret_cast<const float4*>(p0 + dy*PROW);
      A[3*dy+1] = *reinterpret_cast<const float4*>(p0 + dy*PROW + 4);
      A[3*dy+2] = *reinterpret_cast<const float4*>(p0 + dy*PROW + 8);
    }
    for (int t = 0; t < T_; t += 2) {
      {
        const float* p1 = p0 + (size_t)(t + 1)*PTB*B_;
#pragma unroll
        for (int dy = 0; dy < 3; ++dy) {
          Bv[3*dy]   = *reinterpret_cast<const float4*>(p1 + dy*PROW);
          Bv[3*dy+1] = *reinterpret_cast<const float4*>(p1 + dy*PROW + 4);
          Bv[3*dy+2] = *reinterpret_cast<const float4*>(p1 + dy*PROW + 8);
        }
      }
      {                                 // compute t from A
        f2 aa = (f2)0.f, ab = (f2)0.f;
#pragma unroll
        for (int dy = 0; dy < 3; ++dy) {
          const float4 f0 = A[3*dy], f1 = A[3*dy+1], f2v = A[3*dy+2];
          const f2 w0 = w01[dy*6], w0y = w01[dy*6+1], w1 = w01[dy*6+2],
                   w1y = w01[dy*6+3], w2 = w01[dy*6+4], w2y = w01[dy*6+5];
          aa += f0.z*w0 + f0.w*w0y + f1.x*w1 + f1.y*w1y + f1.z*w2 + f1.w*w2y;
          ab += f1.x*w0 + f1.y*w0y + f1.z*w1 + f1.w*w1y + f2v.x*w2 + f2v.y*w2y;
        }
        f2 na = 0.9f*va + aa;
        f2 nb = 0.9f*vb + ab;
        const bool s0a = na.x > 1.f, s1a = na.y > 1.f, s0b = nb.x > 1.f, s1b = nb.y > 1.f;
        va.x = s0a ? na.x - 1.f : na.x;  va.y = s1a ? na.y - 1.f : na.y;
        vb.x = s0b ? nb.x - 1.f : nb.x;  vb.y = s1b ? nb.y - 1.f : nb.y;
        const unsigned packed =
            (unsigned)(__popcll(__ballot(s0a)) + __popcll(__ballot(s0b)))
          | ((unsigned)(__popcll(__ballot(s1a)) + __popcll(__ballot(s1b))) << 16);
        if (l == 0) per_part[obase + (unsigned)t*16384u] = packed;
      }
      if (t + 2 < T_) {
        const float* p2 = p0 + (size_t)(t + 2)*PTB*B_;
#pragma unroll
        for (int dy = 0; dy < 3; ++dy) {
          A[3*dy]   = *reinterpret_cast<const float4*>(p2 + dy*PROW);
          A[3*dy+1] = *reinterpret_cast<const float4*>(p2 + dy*PROW + 4);
          A[3*dy+2] = *reinterpret_cast<const float4*>(p2 + dy*PROW + 8);
        }
      }
      {                                 // compute t+1 from Bv
        f2 aa = (f2)0.f, ab = (f2)0.f;
#pragma unroll
        for (int dy = 0; dy < 3; ++dy) {
          const float4 f0 = Bv[3*dy], f1 = Bv[3*dy+1], f2v = Bv[3*dy+2];
          const f2 w0 = w01[dy*6], w0y = w01[dy*6+1], w1 = w01[dy*6+2],
                   w1y = w01[dy*6+3], w2 = w01[dy*6+4], w2y = w01[dy*6+5];
          aa += f0.z*w0 + f0.w*w0y + f1.x*w1 + f1.y*w1y + f1.z*w2 + f1.w*w2y;
          ab += f1.x*w0 + f1.y*w0y + f1.z*w1 + f1.w*w1y + f2v.x*w2 + f2v.y*w2y;
        }
        f2 na = 0.9f*va + aa;
        f2 nb = 0.9f*vb + ab;
        const bool s0a = na.x > 1.f, s1a = na.y > 1.f, s0b = nb.x > 1.f, s1b = nb.y > 1.f;
        va.x = s0a ? na.x - 1.f : na.x;  va.y = s1a ? na.y - 1.f : na.y;
        vb.x = s0b ? nb.x - 1.f : nb.x;  vb.y = s1b ? nb.y - 1.f : nb.y;
        const unsigned packed =
            (unsigned)(__popcll(__ballot(s0a)) + __popcll(__ballot(s0b)))
          | ((unsigned)(__popcll(__ballot(s1a)) + __popcll(__ballot(s1b))) << 16);
        if (l == 0) per_part[obase + (unsigned)(t + 1)*16384u] = packed;
      }
    }
  }
}

// ---------------- K3: reduce partials + logits ----------------
__global__ void __launch_bounds__(256) k_logits(const float* __restrict__ scores,
    const unsigned* __restrict__ fov_part, const unsigned* __restrict__ per_part,
    const float* __restrict__ head_w, const float* __restrict__ head_b,
    const float* __restrict__ route_w, const float* __restrict__ route_b,
    float* __restrict__ logits, unsigned* __restrict__ tot) {
  const int tb = blockIdx.x, tid = threadIdx.x;
  __shared__ float sc[NP_];
  __shared__ float fu[96];
  sc[tid] = scores[tb*NP_ + tid];
  if (tid < 64) {
    const unsigned* fp = fov_part + (size_t)tb*256;   // 32 cp * 8
    const int cp = tid >> 1, sh = (tid & 1)*16;
    unsigned fsum = 0;
#pragma unroll
    for (int i = 0; i < 8; ++i) fsum += (fp[cp*8 + i] >> sh) & 0xFFFFu;
    fu[tid] = (float)fsum * (1.f/1024.f);
    unsigned r = fsum;
#pragma unroll
    for (int off = 32; off > 0; off >>= 1) r += __shfl_down(r, off);
    if (tid == 0) atomicAdd(&tot[0], r);
  } else if (tid < 128) {
    const int c = tid - 64;            // only c<32 active
    unsigned psum = 0;
    if (c < 32) {
      const unsigned* pp = per_part + (size_t)tb*512;  // 16 cp * 32
      const int cp = c >> 1, sh = (c & 1)*16;
#pragma unroll 8
      for (int i = 0; i < 32; ++i) psum += (pp[cp*32 + i] >> sh) & 0xFFFFu;
      fu[64 + c] = (float)psum * (1.f/4096.f);
    }
    unsigned r = psum;
#pragma unroll
    for (int off = 32; off > 0; off >>= 1) r += __shfl_down(r, off);
    if (tid == 64) atomicAdd(&tot[1], r);
  }
  __syncthreads();
  if (tid < 128) {
    const int o = tid;
    float acc = head_b[o] + route_b[o];
#pragma unroll 8
    for (int k = 0; k < 96; ++k)  acc += fu[k]*head_w[k*OUT_ + o];
#pragma unroll 8
    for (int p = 0; p < NP_; ++p) acc += sc[p]*route_w[p*OUT_ + o];
    logits[tb*OUT_ + o] = acc;
  }
}

// ---------------- K4: finalize ----------------
__global__ void __launch_bounds__(256) k_final(const float* __restrict__ logits,
    float* __restrict__ dout, const unsigned* __restrict__ cnts) {
  const int blk = blockIdx.x, tid = threadIdx.x;
  if (blk < 16) {
    const int idx = blk*256 + tid;
    const int b = idx >> 7, o = idx & 127;
    float s = 0.f;
#pragma unroll
    for (int t = 0; t < T_; ++t) s += logits[(t*B_ + b)*OUT_ + o];
    dout[idx] = s * (1.f/32.f);
  } else {
    if (tid == 0) {
      dout[OFF_SR]     = (float)cnts[321] * (1.f/67108864.f);   // T*B*32*32*64
      dout[OFF_SR + 1] = (float)cnts[322] * (1.f/134217728.f);  // T*B*64*64*32
      dout[OFF_ACTIVE] = (float)cnts[0]   * (1.f/33554432.f);   // T*B*H*W*C
    }
    dout[OFF_ROUTE + tid] = (float)cnts[1 + tid] * (1.f/1024.f);
    if (tid < 64) dout[OFF_CHAN + tid] = (float)cnts[257 + tid] * (1.f/1024.f);
  }
}

extern "C" void kernel_launch(void* const* d_in, const int* in_sizes, int n_in,
                              void* d_out, int out_size, void* d_ws, size_t ws_size,
                              hipStream_t stream) {
  const float* x       = (const float*)d_in[0];
  const float* wf      = (const float*)d_in[1];
  const float* wp      = (const float*)d_in[2];
  const float* head_w  = (const float*)d_in[3];
  const float* head_b  = (const float*)d_in[4];
  const float* route_w = (const float*)d_in[5];
  const float* route_b = (const float*)d_in[6];
  float* out = (float*)d_out;

  float*    ws_P      = (float*)d_ws;                         // 1024*8976 floats (36.8 MB)
  float*    ws_Wf     = ws_P + (size_t)1024*PTB;              // 1024*2312 floats (9.5 MB)
  float*    ws_scores = ws_Wf + (size_t)1024*WTB;             // 262144 floats
  float*    ws_gate   = ws_scores + T_*B_*NP_;                // 65536 floats
  unsigned* fov_part  = (unsigned*)(ws_gate + T_*B_*CF_);     // 32*32*32*8 u32 (1 MB)
  unsigned* per_part  = fov_part + (size_t)T_*B_*256;         // 32*32*16*32 u32 (2 MB)
  unsigned* ws_cnt    = per_part + (size_t)T_*B_*512;

  hipMemsetAsync(ws_cnt, 0, CNT_N*sizeof(unsigned), stream);

  k_pre   <<<T_*B_, 256, 0, stream>>>(x, wf, ws_scores, ws_P, ws_Wf, ws_gate, ws_cnt);
  k_mem   <<<6144,  256, 0, stream>>>(ws_Wf, ws_P, wf, wp, ws_gate, fov_part, per_part);
  k_logits<<<T_*B_, 256, 0, stream>>>(ws_scores, fov_part, per_part, head_w, head_b,
                                      route_w, route_b, out + OFF_LOGITS, ws_cnt + 321);
  k_final <<<17, 256, 0, stream>>>(out + OFF_LOGITS, out, ws_cnt);
}